// Round 1
// baseline (886.009 us; speedup 1.0000x reference)
//
#include <hip/hip_runtime.h>
#include <math.h>

// B=2,S=2048 -> NT=4096 tokens; K=8, D=1024, P=32, KP=4, DFF=4096
typedef unsigned short ushort_t;
typedef __attribute__((ext_vector_type(8))) short short8;
typedef __attribute__((ext_vector_type(4))) float floatx4;

static __device__ __forceinline__ float bf2f(ushort_t h){
  return __uint_as_float(((unsigned int)h) << 16);
}
static __device__ __forceinline__ ushort_t f2bf(float f){
  unsigned int u = __float_as_uint(f);
  unsigned int r = u + 0x7FFFu + ((u >> 16) & 1u);   // round-to-nearest-even
  return (ushort_t)(r >> 16);
}

static __device__ __forceinline__ void gload16(const void* g, void* l){
  __builtin_amdgcn_global_load_lds((const __attribute__((address_space(1))) void*)g,
                                   (__attribute__((address_space(3))) void*)l, 16, 0, 0);
}

// ---------------- fp32 -> bf16 convert (4 elems/thread) ----------------
__global__ __launch_bounds__(256) void k_cvt_bf16(const float* __restrict__ in,
                                                  ushort_t* __restrict__ out, int n4){
  int i = blockIdx.x * 256 + threadIdx.x;
  if (i < n4){
    float4 v = ((const float4*)in)[i];
    unsigned long long p = (unsigned long long)f2bf(v.x)
                         | ((unsigned long long)f2bf(v.y) << 16)
                         | ((unsigned long long)f2bf(v.z) << 32)
                         | ((unsigned long long)f2bf(v.w) << 48);
    ((unsigned long long*)out)[i] = p;
  }
}

// ---------------- 1024x1024 transpose with bf16 convert ----------------
__global__ __launch_bounds__(256) void k_transpose_cvt(const float* __restrict__ in,
                                                       ushort_t* __restrict__ out){
  __shared__ float tile[32][33];
  int bx = blockIdx.x * 32, by = blockIdx.y * 32;
  int tx = threadIdx.x & 31, ty = threadIdx.x >> 5;   // ty 0..7
  for (int i = 0; i < 32; i += 8)
    tile[ty + i][tx] = in[(size_t)(by + ty + i) * 1024 + bx + tx];
  __syncthreads();
  for (int i = 0; i < 32; i += 8)
    out[(size_t)(bx + ty + i) * 1024 + by + tx] = f2bf(tile[tx][ty + i]);
}

// w[d] = sum_e bq[e] * Wk[e][d]   (grid 4 x 256)
__global__ __launch_bounds__(256) void k_wvec(const float* __restrict__ bq,
                                              const float* __restrict__ Wk,
                                              float* __restrict__ wv){
  int d = blockIdx.x * 256 + threadIdx.x;
  float a = 0.f;
  for (int e = 0; e < 1024; e++) a += bq[e] * Wk[(size_t)e * 1024 + d];
  wv[d] = a;
}

// pb[p] = pattern[p] . bv   (1 block x 256)
__global__ __launch_bounds__(256) void k_pb(const float* __restrict__ pat,
                                            const float* __restrict__ bv,
                                            float* __restrict__ pb){
  int t = threadIdx.x, p = t >> 3, s = t & 7;
  float a = 0.f;
  for (int e = s; e < 1024; e += 8) a += pat[p * 1024 + e] * bv[e];
  a += __shfl_xor(a, 1); a += __shfl_xor(a, 2); a += __shfl_xor(a, 4);
  if (s == 0) pb[p] = a;
}

// PV[p][d] = sum_e pattern[p][e]*Wv[e][d]  -> bf16   (grid (4,32))
__global__ __launch_bounds__(256) void k_pv(const float* __restrict__ pat,
                                            const float* __restrict__ Wv,
                                            ushort_t* __restrict__ PVb){
  int d = blockIdx.x * 256 + threadIdx.x;
  int p = blockIdx.y;
  const float* pr = pat + p * 1024;
  float a = 0.f;
  for (int e = 0; e < 1024; e++) a += pr[e] * Wv[(size_t)e * 1024 + d];
  PVb[p * 1024 + d] = f2bf(a);
}

// ---------------- main bf16 GEMM: out[m][n] = sum_k A[m][k]*B[n][k] ----------------
// MODE 0: store bf16(acc)
// MODE 1: store bf16(acc + bias[n])
// MODE 2: store bf16(acc + bias[n] + Xadd[m*N+n])
// MODE 3: store bf16(gelu(acc + bias[n]))
// MODE 4: store fp32 (acc + bias[n])
template<int MODE>
__global__ __launch_bounds__(256) void k_gemm_bt(const ushort_t* __restrict__ A,
                                                 const ushort_t* __restrict__ B,
                                                 void* __restrict__ C,
                                                 const float* __restrict__ bias,
                                                 const float* __restrict__ Xadd,
                                                 int M, int N, int K){
  (void)M;
  __shared__ ushort_t As[128 * 32];
  __shared__ ushort_t Bs[128 * 32];
  const int tid = threadIdx.x;
  const int w = tid >> 6, l = tid & 63;
  const int m0 = blockIdx.y << 7, n0 = blockIdx.x << 7;
  const int wm = (w >> 1) << 6, wn = (w & 1) << 6;
  const int rA = (w << 4) + (l >> 2);   // staging row 0..63 (+64 second round)
  const int cA = (l & 3) << 3;          // staging col in elems
  const int fr = l & 15, fq = l >> 4;

  floatx4 acc[4][4];
#pragma unroll
  for (int i = 0; i < 4; i++)
#pragma unroll
    for (int j = 0; j < 4; j++) acc[i][j] = (floatx4)0.0f;

  const ushort_t* Ab = A + (size_t)(m0 + rA) * K + cA;
  const ushort_t* Bb = B + (size_t)(n0 + rA) * K + cA;
  const size_t row64 = (size_t)64 * K;
  ushort_t* Asw = As + (w << 9);
  ushort_t* Bsw = Bs + (w << 9);

  for (int k0 = 0; k0 < K; k0 += 32){
    __syncthreads();
    gload16(Ab + k0, Asw);
    gload16(Ab + row64 + k0, Asw + 2048);
    gload16(Bb + k0, Bsw);
    gload16(Bb + row64 + k0, Bsw + 2048);
    __syncthreads();
    short8 af[4], bg[4];
#pragma unroll
    for (int i = 0; i < 4; i++){
      af[i] = *(const short8*)(As + ((wm + (i << 4) + fr) << 5) + (fq << 3));
      bg[i] = *(const short8*)(Bs + ((wn + (i << 4) + fr) << 5) + (fq << 3));
    }
#pragma unroll
    for (int i = 0; i < 4; i++)
#pragma unroll
      for (int j = 0; j < 4; j++)
        acc[i][j] = __builtin_amdgcn_mfma_f32_16x16x32_bf16(af[i], bg[j], acc[i][j], 0, 0, 0);
  }

#pragma unroll
  for (int i = 0; i < 4; i++){
    int row = m0 + wm + (i << 4) + (fq << 2);
#pragma unroll
    for (int j = 0; j < 4; j++){
      int col = n0 + wn + (j << 4) + fr;
      float b = (MODE >= 1) ? bias[col] : 0.0f;
#pragma unroll
      for (int r = 0; r < 4; r++){
        float v = acc[i][j][r] + b;
        size_t idx = (size_t)(row + r) * N + col;
        if (MODE == 2) v += Xadd[idx];
        if (MODE == 3) v = 0.5f * v * (1.0f + erff(v * 0.70710678118654752f));
        if (MODE == 4) ((float*)C)[idx] = v;
        else           ((ushort_t*)C)[idx] = f2bf(v);
      }
    }
  }
}

// ---------------- skinny N=32 GEMM: C[m][p] = sum_k A[m][k]*B[p][k] (+ bvec[p]) ----------------
template<bool ADDB>
__global__ __launch_bounds__(256) void k_gemm_n32(const ushort_t* __restrict__ A,
                                                  const ushort_t* __restrict__ B,
                                                  float* __restrict__ C,
                                                  const float* __restrict__ bvec,
                                                  int M, int K){
  (void)M;
  __shared__ ushort_t As[128 * 32];
  __shared__ ushort_t Bs[32 * 32];
  const int tid = threadIdx.x;
  const int w = tid >> 6, l = tid & 63;
  const int m0 = blockIdx.x << 7;
  const int rA = (w << 4) + (l >> 2);
  const int cA = (l & 3) << 3;
  const int fr = l & 15, fq = l >> 4;

  floatx4 acc[2][2];
#pragma unroll
  for (int i = 0; i < 2; i++)
#pragma unroll
    for (int j = 0; j < 2; j++) acc[i][j] = (floatx4)0.0f;

  const ushort_t* Ab = A + (size_t)(m0 + rA) * K + cA;
  const ushort_t* Bb = B + (size_t)rA * K + cA;    // valid rows only for w<2
  const size_t row64 = (size_t)64 * K;

  for (int k0 = 0; k0 < K; k0 += 32){
    __syncthreads();
    gload16(Ab + k0, As + (w << 9));
    gload16(Ab + row64 + k0, As + 2048 + (w << 9));
    if (w < 2) gload16(Bb + k0, Bs + (w << 9));
    __syncthreads();
    short8 af[2], bg[2];
#pragma unroll
    for (int i = 0; i < 2; i++)
      af[i] = *(const short8*)(As + (((w << 5) + (i << 4) + fr) << 5) + (fq << 3));
#pragma unroll
    for (int j = 0; j < 2; j++)
      bg[j] = *(const short8*)(Bs + (((j << 4) + fr) << 5) + (fq << 3));
#pragma unroll
    for (int i = 0; i < 2; i++)
#pragma unroll
      for (int j = 0; j < 2; j++)
        acc[i][j] = __builtin_amdgcn_mfma_f32_16x16x32_bf16(af[i], bg[j], acc[i][j], 0, 0, 0);
  }

#pragma unroll
  for (int i = 0; i < 2; i++){
    int row = m0 + (w << 5) + (i << 4) + (fq << 2);
#pragma unroll
    for (int j = 0; j < 2; j++){
      int col = (j << 4) + fr;
      float b = ADDB ? bvec[col] : 0.0f;
#pragma unroll
      for (int r = 0; r < 4; r++)
        C[(size_t)(row + r) * 32 + col] = acc[i][j][r] + b;
    }
  }
}

// ---------------- per-token attention / pattern / top-k (fp32) ----------------
// logits[i][j] = T'[i].SN[j]/32 ; attn=softmax ; nps[p][q]=(1/32)sum_k attn[q][k]*NPRE[k][p]
// scores = 0.5*(nps.tw) + 0.5*CB ; top4 -> weights ; final_attn ; g = fa@attn ; gsn = g@SN
#define SNP 1032   // padded LDS row pitch (floats / ushorts)
__global__ __launch_bounds__(256) void k_token(const ushort_t* __restrict__ T,
                                               const float* __restrict__ SN,
                                               const float* __restrict__ NPRE,
                                               const float* __restrict__ CB,
                                               const float* __restrict__ TW,
                                               ushort_t* __restrict__ GSN){
  __shared__ float snf[8 * SNP];
  __shared__ ushort_t tb[8 * SNP];
  __shared__ float logit_s[64], attn_s[64], nprs[256], nps_s[256];
  __shared__ float sc_s[32], cb_s[32], tw_s[8];
  __shared__ int   sel_s[4];
  __shared__ float tkw_s[4], rmax_s[4], rsum_s[4], fa_s[8], g_s[8];

  const int t = threadIdx.x;
  const int tok = blockIdx.x;

  // loads
  const float* SNg = SN + (size_t)tok * 8192;
#pragma unroll
  for (int k = 0; k < 8; k++){
    float4 v = ((const float4*)SNg)[k * 256 + t];
    *((float4*)(snf + k * SNP + (t << 2))) = v;
  }
  const ushort_t* Tg = T + (size_t)tok * 8192;
#pragma unroll
  for (int pass = 0; pass < 4; pass++){
    int k = (pass << 1) + (t >> 7), c = t & 127;
    uint4 v = ((const uint4*)Tg)[k * 128 + c];
    *((uint4*)(tb + k * SNP + (c << 3))) = v;
  }
  nprs[t] = NPRE[(size_t)tok * 256 + t];
  if (t < 32) cb_s[t] = CB[tok * 32 + t];
  if (t < 8)  tw_s[t] = TW[tok * 8 + t];
  __syncthreads();

  { // logits: 64 pairs x 4 threads
    int q = t >> 2, s = t & 3, i = q >> 3, j = q & 7;
    const ushort_t* Ti = tb + i * SNP;
    const float* Sj = snf + j * SNP;
    float a = 0.f;
    for (int d = s; d < 1024; d += 4) a += bf2f(Ti[d]) * Sj[d];
    a += __shfl_xor(a, 1); a += __shfl_xor(a, 2);
    if (s == 0) logit_s[q] = a * 0.03125f;
  }
  __syncthreads();
  if (t < 8){ // softmax rows
    float m = -1e30f;
    for (int j = 0; j < 8; j++) m = fmaxf(m, logit_s[t * 8 + j]);
    float e[8], s = 0.f;
    for (int j = 0; j < 8; j++){ e[j] = expf(logit_s[t * 8 + j] - m); s += e[j]; }
    float inv = 1.f / s;
    for (int j = 0; j < 8; j++) attn_s[t * 8 + j] = e[j] * inv;
  }
  __syncthreads();
  { // nps
    int p = t >> 3, q = t & 7;
    float a = 0.f;
    for (int k = 0; k < 8; k++) a += attn_s[q * 8 + k] * nprs[k * 32 + p];
    nps_s[p * 8 + q] = a * 0.03125f;
  }
  __syncthreads();
  if (t < 32){
    float nb = 0.f;
    for (int q = 0; q < 8; q++) nb += nps_s[t * 8 + q] * tw_s[q];
    sc_s[t] = 0.5f * nb + 0.5f * cb_s[t];
  }
  __syncthreads();
  if (t == 0){ // top-4 (stable: first index wins ties, like lax.top_k)
    unsigned used = 0; float vals[4]; int idx[4];
    for (int kp = 0; kp < 4; kp++){
      float best = -1e30f; int bi = 0;
      for (int p = 0; p < 32; p++)
        if (!((used >> p) & 1u) && sc_s[p] > best){ best = sc_s[p]; bi = p; }
      used |= 1u << bi; vals[kp] = best; idx[kp] = bi;
    }
    float m = vals[0], s = 0.f, e[4];
    for (int kp = 0; kp < 4; kp++){ e[kp] = expf(vals[kp] - m); s += e[kp]; }
    for (int kp = 0; kp < 4; kp++){ tkw_s[kp] = e[kp] / s; sel_s[kp] = idx[kp]; }
  }
  __syncthreads();
  if (t < 4){ // row softmax stats for selected patterns
    int p = sel_s[t];
    float m = -1e30f;
    for (int q = 0; q < 8; q++) m = fmaxf(m, nps_s[p * 8 + q]);
    float s = 0.f;
    for (int q = 0; q < 8; q++) s += expf(nps_s[p * 8 + q] - m);
    rmax_s[t] = m; rsum_s[t] = s;
  }
  __syncthreads();
  if (t < 8){ // final_attn
    float f = 0.f;
    for (int kp = 0; kp < 4; kp++){
      int p = sel_s[kp];
      f += tkw_s[kp] * expf(nps_s[p * 8 + t] - rmax_s[kp]) / rsum_s[kp];
    }
    fa_s[t] = f;
  }
  __syncthreads();
  if (t < 8){ // g = fa @ attn
    float g = 0.f;
    for (int q = 0; q < 8; q++) g += fa_s[q] * attn_s[q * 8 + t];
    g_s[t] = g;
  }
  __syncthreads();
  { // gsn = g @ SN  -> bf16
    int d0 = t << 2;
    float o0 = 0, o1 = 0, o2 = 0, o3 = 0;
    for (int k = 0; k < 8; k++){
      float gk = g_s[k];
      const float* S = snf + k * SNP + d0;
      o0 += gk * S[0]; o1 += gk * S[1]; o2 += gk * S[2]; o3 += gk * S[3];
    }
    uint2 pk;
    pk.x = (unsigned)f2bf(o0) | ((unsigned)f2bf(o1) << 16);
    pk.y = (unsigned)f2bf(o2) | ((unsigned)f2bf(o3) << 16);
    *((uint2*)(GSN + (size_t)tok * 1024 + d0)) = pk;
  }
}

extern "C" void kernel_launch(void* const* d_in, const int* in_sizes, int n_in,
                              void* d_out, int out_size, void* d_ws, size_t ws_size,
                              hipStream_t stream){
  (void)in_sizes; (void)n_in; (void)out_size; (void)ws_size;
  const float* x   = (const float*)d_in[0];
  const float* tw  = (const float*)d_in[3];
  const float* SN  = (const float*)d_in[4];
  const float* ctx = (const float*)d_in[5];
  const float* Wq  = (const float*)d_in[6];
  const float* bq  = (const float*)d_in[7];
  const float* Wk  = (const float*)d_in[8];
  const float* bv  = (const float*)d_in[11];
  const float* Wv  = (const float*)d_in[10];
  const float* pat = (const float*)d_in[12];
  const float* Wup = (const float*)d_in[13];
  const float* bup = (const float*)d_in[14];
  const float* Wdn = (const float*)d_in[15];
  const float* bdn = (const float*)d_in[16];
  float* out = (float*)d_out;

  char* ws = (char*)d_ws;
  size_t off = 0;
  auto alloc = [&](size_t bytes) -> char* {
    char* p = ws + off;
    off = (off + bytes + 255) & ~(size_t)255;
    return p;
  };
  ushort_t* SNB  = (ushort_t*)alloc(67108864);  // SN bf16 [32768][1024]; later aliased by H
  ushort_t* TB   = (ushort_t*)alloc(67108864);  // T bf16; later aliased by COMBINED
  float*    NPRE = (float*)alloc(4194304);      // [32768][32]
  float*    CBb  = (float*)alloc(524288);       // [4096][32]
  ushort_t* GSN  = (ushort_t*)alloc(8388608);   // [4096][1024] bf16
  ushort_t* CTXB = (ushort_t*)alloc(8388608);
  ushort_t* PATB = (ushort_t*)alloc(65536);
  ushort_t* WVB  = (ushort_t*)alloc(2097152);
  ushort_t* WUPB = (ushort_t*)alloc(8388608);
  ushort_t* WDNB = (ushort_t*)alloc(8388608);
  ushort_t* ATB  = (ushort_t*)alloc(2097152);
  ushort_t* WKTB = (ushort_t*)alloc(2097152);
  ushort_t* WQTB = (ushort_t*)alloc(2097152);
  ushort_t* PVB  = (ushort_t*)alloc(65536);
  float*    WVEC = (float*)alloc(4096);
  float*    PBv  = (float*)alloc(128);
  ushort_t* H    = SNB;   // 32MB alias (SNB dead by FFN time)
  ushort_t* CMB  = TB;    // 8MB alias (T dead after k_token)

  // dtype converts / transposes
  k_cvt_bf16<<<32768, 256, 0, stream>>>(SN,  SNB,  8388608);
  k_cvt_bf16<<<4096,  256, 0, stream>>>(ctx, CTXB, 1048576);
  k_cvt_bf16<<<32,    256, 0, stream>>>(pat, PATB, 8192);
  k_cvt_bf16<<<1024,  256, 0, stream>>>(Wv,  WVB,  262144);
  k_cvt_bf16<<<4096,  256, 0, stream>>>(Wup, WUPB, 1048576);
  k_cvt_bf16<<<4096,  256, 0, stream>>>(Wdn, WDNB, 1048576);
  k_transpose_cvt<<<dim3(32, 32), 256, 0, stream>>>(Wq, WQTB);
  k_transpose_cvt<<<dim3(32, 32), 256, 0, stream>>>(Wk, WKTB);
  k_wvec<<<4, 256, 0, stream>>>(bq, Wk, WVEC);
  k_pb<<<1, 256, 0, stream>>>(pat, bv, PBv);
  k_pv<<<dim3(4, 32), 256, 0, stream>>>(pat, Wv, PVB);

  // At[d'][d] = sum_e Wk[e][d']*Wq[e][d]
  k_gemm_bt<0><<<dim3(8, 8), 256, 0, stream>>>(WKTB, WQTB, ATB, nullptr, nullptr, 1024, 1024, 1024);
  // T = SN @ At^T + wvec  (wvec folds the bq-row bias; row-constant terms cancel in softmax)
  k_gemm_bt<1><<<dim3(8, 256), 256, 0, stream>>>(SNB, ATB, TB, WVEC, nullptr, 32768, 1024, 1024);
  // NPRE[m][p] = SN[m] . PV[p] + pb[p]
  k_gemm_n32<true><<<256, 256, 0, stream>>>(SNB, PVB, NPRE, PBv, 32768, 1024);
  // CB[tok][p] = context[tok] . pattern[p]
  k_gemm_n32<false><<<32, 256, 0, stream>>>(CTXB, PATB, CBb, nullptr, 4096, 1024);
  // per-token attention / top-k -> gsn
  k_token<<<4096, 256, 0, stream>>>(TB, SN, NPRE, CBb, tw, GSN);
  // combined = gsn @ Wv^T + bv + x   (bf16)
  k_gemm_bt<2><<<dim3(8, 32), 256, 0, stream>>>(GSN, WVB, CMB, bv, x, 4096, 1024, 1024);
  // H = gelu(combined @ Wup^T + bup) (bf16)
  k_gemm_bt<3><<<dim3(32, 32), 256, 0, stream>>>(CMB, WUPB, H, bup, nullptr, 4096, 4096, 1024);
  // out = H @ Wdown^T + bdown        (fp32)
  k_gemm_bt<4><<<dim3(8, 32), 256, 0, stream>>>(H, WDNB, out, bdn, nullptr, 4096, 1024, 4096);
}

// Round 2
// 763.658 us; speedup vs baseline: 1.1602x; 1.1602x over previous
//
#include <hip/hip_runtime.h>
#include <math.h>

// B=2,S=2048 -> NT=4096 tokens; K=8, D=1024, P=32, KP=4, DFF=4096
typedef unsigned short ushort_t;
typedef __attribute__((ext_vector_type(8))) short short8;
typedef __attribute__((ext_vector_type(4))) float floatx4;

static __device__ __forceinline__ float bf2f(ushort_t h){
  return __uint_as_float(((unsigned int)h) << 16);
}
static __device__ __forceinline__ ushort_t f2bf(float f){
  unsigned int u = __float_as_uint(f);
  unsigned int r = u + 0x7FFFu + ((u >> 16) & 1u);   // round-to-nearest-even
  return (ushort_t)(r >> 16);
}

static __device__ __forceinline__ void gload16(const void* g, void* l){
  __builtin_amdgcn_global_load_lds((const __attribute__((address_space(1))) void*)g,
                                   (__attribute__((address_space(3))) void*)l, 16, 0, 0);
}

// ---------------- fp32 -> bf16 convert (4 elems/thread) ----------------
__global__ __launch_bounds__(256) void k_cvt_bf16(const float* __restrict__ in,
                                                  ushort_t* __restrict__ out, int n4){
  int i = blockIdx.x * 256 + threadIdx.x;
  if (i < n4){
    float4 v = ((const float4*)in)[i];
    unsigned long long p = (unsigned long long)f2bf(v.x)
                         | ((unsigned long long)f2bf(v.y) << 16)
                         | ((unsigned long long)f2bf(v.z) << 32)
                         | ((unsigned long long)f2bf(v.w) << 48);
    ((unsigned long long*)out)[i] = p;
  }
}

// ---------------- 1024x1024 transpose with bf16 convert ----------------
__global__ __launch_bounds__(256) void k_transpose_cvt(const float* __restrict__ in,
                                                       ushort_t* __restrict__ out){
  __shared__ float tile[32][33];
  int bx = blockIdx.x * 32, by = blockIdx.y * 32;
  int tx = threadIdx.x & 31, ty = threadIdx.x >> 5;   // ty 0..7
  for (int i = 0; i < 32; i += 8)
    tile[ty + i][tx] = in[(size_t)(by + ty + i) * 1024 + bx + tx];
  __syncthreads();
  for (int i = 0; i < 32; i += 8)
    out[(size_t)(bx + ty + i) * 1024 + by + tx] = f2bf(tile[tx][ty + i]);
}

// w[d] = sum_e bq[e] * Wk[e][d]   (grid 4 x 256)
__global__ __launch_bounds__(256) void k_wvec(const float* __restrict__ bq,
                                              const float* __restrict__ Wk,
                                              float* __restrict__ wv){
  int d = blockIdx.x * 256 + threadIdx.x;
  float a = 0.f;
  for (int e = 0; e < 1024; e++) a += bq[e] * Wk[(size_t)e * 1024 + d];
  wv[d] = a;
}

// pb[p] = pattern[p] . bv   (1 block x 256)
__global__ __launch_bounds__(256) void k_pb(const float* __restrict__ pat,
                                            const float* __restrict__ bv,
                                            float* __restrict__ pb){
  int t = threadIdx.x, p = t >> 3, s = t & 7;
  float a = 0.f;
  for (int e = s; e < 1024; e += 8) a += pat[p * 1024 + e] * bv[e];
  a += __shfl_xor(a, 1); a += __shfl_xor(a, 2); a += __shfl_xor(a, 4);
  if (s == 0) pb[p] = a;
}

// PV[p][d] = sum_e pattern[p][e]*Wv[e][d]  -> bf16   (grid (4,32))
__global__ __launch_bounds__(256) void k_pv(const float* __restrict__ pat,
                                            const float* __restrict__ Wv,
                                            ushort_t* __restrict__ PVb){
  int d = blockIdx.x * 256 + threadIdx.x;
  int p = blockIdx.y;
  const float* pr = pat + p * 1024;
  float a = 0.f;
  for (int e = 0; e < 1024; e++) a += pr[e] * Wv[(size_t)e * 1024 + d];
  PVb[p * 1024 + d] = f2bf(a);
}

// ---------------- main bf16 GEMM: out[m][n] = sum_k A[m][k]*B[n][k] ----------------
// MODE 0: store bf16(acc)
// MODE 1: store bf16(acc + bias[n])
// MODE 2: store bf16(acc + bias[n] + Xadd[m*N+n])
// MODE 3: store bf16(gelu(acc + bias[n]))
// MODE 4: store fp32 (acc + bias[n])
template<int MODE>
__global__ __launch_bounds__(256) void k_gemm_bt(const ushort_t* __restrict__ A,
                                                 const ushort_t* __restrict__ B,
                                                 void* __restrict__ C,
                                                 const float* __restrict__ bias,
                                                 const float* __restrict__ Xadd,
                                                 int M, int N, int K){
  (void)M;
  __shared__ ushort_t As[128 * 32];
  __shared__ ushort_t Bs[128 * 32];
  const int tid = threadIdx.x;
  const int w = tid >> 6, l = tid & 63;
  const int m0 = blockIdx.y << 7, n0 = blockIdx.x << 7;
  const int wm = (w >> 1) << 6, wn = (w & 1) << 6;
  const int rA = (w << 4) + (l >> 2);   // staging row 0..63 (+64 second round)
  const int cA = (l & 3) << 3;          // staging col in elems
  const int fr = l & 15, fq = l >> 4;

  floatx4 acc[4][4];
#pragma unroll
  for (int i = 0; i < 4; i++)
#pragma unroll
    for (int j = 0; j < 4; j++) acc[i][j] = (floatx4)0.0f;

  const ushort_t* Ab = A + (size_t)(m0 + rA) * K + cA;
  const ushort_t* Bb = B + (size_t)(n0 + rA) * K + cA;
  const size_t row64 = (size_t)64 * K;
  ushort_t* Asw = As + (w << 9);
  ushort_t* Bsw = Bs + (w << 9);

  for (int k0 = 0; k0 < K; k0 += 32){
    __syncthreads();
    gload16(Ab + k0, Asw);
    gload16(Ab + row64 + k0, Asw + 2048);
    gload16(Bb + k0, Bsw);
    gload16(Bb + row64 + k0, Bsw + 2048);
    __syncthreads();
    short8 af[4], bg[4];
#pragma unroll
    for (int i = 0; i < 4; i++){
      af[i] = *(const short8*)(As + ((wm + (i << 4) + fr) << 5) + (fq << 3));
      bg[i] = *(const short8*)(Bs + ((wn + (i << 4) + fr) << 5) + (fq << 3));
    }
#pragma unroll
    for (int i = 0; i < 4; i++)
#pragma unroll
      for (int j = 0; j < 4; j++)
        acc[i][j] = __builtin_amdgcn_mfma_f32_16x16x32_bf16(af[i], bg[j], acc[i][j], 0, 0, 0);
  }

#pragma unroll
  for (int i = 0; i < 4; i++){
    int row = m0 + wm + (i << 4) + (fq << 2);
#pragma unroll
    for (int j = 0; j < 4; j++){
      int col = n0 + wn + (j << 4) + fr;
      float b = (MODE >= 1) ? bias[col] : 0.0f;
#pragma unroll
      for (int r = 0; r < 4; r++){
        float v = acc[i][j][r] + b;
        size_t idx = (size_t)(row + r) * N + col;
        if (MODE == 2) v += Xadd[idx];
        if (MODE == 3) v = 0.5f * v * (1.0f + erff(v * 0.70710678118654752f));
        if (MODE == 4) ((float*)C)[idx] = v;
        else           ((ushort_t*)C)[idx] = f2bf(v);
      }
    }
  }
}

// ---------------- skinny N=32 GEMM: C[m][p] = sum_k A[m][k]*B[p][k] (+ bvec[p]) ----------------
template<bool ADDB>
__global__ __launch_bounds__(256) void k_gemm_n32(const ushort_t* __restrict__ A,
                                                  const ushort_t* __restrict__ B,
                                                  float* __restrict__ C,
                                                  const float* __restrict__ bvec,
                                                  int M, int K){
  (void)M;
  __shared__ ushort_t As[128 * 32];
  __shared__ ushort_t Bs[32 * 32];
  const int tid = threadIdx.x;
  const int w = tid >> 6, l = tid & 63;
  const int m0 = blockIdx.x << 7;
  const int rA = (w << 4) + (l >> 2);
  const int cA = (l & 3) << 3;
  const int fr = l & 15, fq = l >> 4;

  floatx4 acc[2][2];
#pragma unroll
  for (int i = 0; i < 2; i++)
#pragma unroll
    for (int j = 0; j < 2; j++) acc[i][j] = (floatx4)0.0f;

  const ushort_t* Ab = A + (size_t)(m0 + rA) * K + cA;
  const ushort_t* Bb = B + (size_t)rA * K + cA;    // valid rows only for w<2
  const size_t row64 = (size_t)64 * K;

  for (int k0 = 0; k0 < K; k0 += 32){
    __syncthreads();
    gload16(Ab + k0, As + (w << 9));
    gload16(Ab + row64 + k0, As + 2048 + (w << 9));
    if (w < 2) gload16(Bb + k0, Bs + (w << 9));
    __syncthreads();
    short8 af[2], bg[2];
#pragma unroll
    for (int i = 0; i < 2; i++)
      af[i] = *(const short8*)(As + (((w << 5) + (i << 4) + fr) << 5) + (fq << 3));
#pragma unroll
    for (int j = 0; j < 2; j++)
      bg[j] = *(const short8*)(Bs + (((j << 4) + fr) << 5) + (fq << 3));
#pragma unroll
    for (int i = 0; i < 2; i++)
#pragma unroll
      for (int j = 0; j < 2; j++)
        acc[i][j] = __builtin_amdgcn_mfma_f32_16x16x32_bf16(af[i], bg[j], acc[i][j], 0, 0, 0);
  }

#pragma unroll
  for (int i = 0; i < 2; i++){
    int row = m0 + (w << 5) + (i << 4) + (fq << 2);
#pragma unroll
    for (int j = 0; j < 2; j++){
      int col = (j << 4) + fr;
      float b = ADDB ? bvec[col] : 0.0f;
#pragma unroll
      for (int r = 0; r < 4; r++)
        C[(size_t)(row + r) * 32 + col] = acc[i][j][r] + b;
    }
  }
}

// ---------------- batched token-pair logits via MFMA (no LDS) ----------------
// pair p covers tokens 2p, 2p+1: rows 16p..16p+15 of T and SNB.
// D[i][j] = T_row(16p+i) . SN_row(16p+j); diagonal 8x8 blocks are the two
// tokens' logit matrices. Stores full 16x16 (scaled by 1/32) to Lg[p][256].
__global__ __launch_bounds__(256) void k_logits(const ushort_t* __restrict__ T,
                                                const ushort_t* __restrict__ SNB,
                                                float* __restrict__ Lg){
  const int w = threadIdx.x >> 6, l = threadIdx.x & 63;
  const int pair = blockIdx.x * 4 + w;           // 0..2047
  const size_t rbase = (size_t)pair * 16 + (l & 15);
  const int ko = (l >> 4) << 3;
  const ushort_t* Ap = T   + rbase * 1024 + ko;
  const ushort_t* Bp = SNB + rbase * 1024 + ko;
  floatx4 acc = (floatx4)0.0f;
#pragma unroll 4
  for (int k0 = 0; k0 < 1024; k0 += 32){
    short8 a = *(const short8*)(Ap + k0);
    short8 b = *(const short8*)(Bp + k0);
    acc = __builtin_amdgcn_mfma_f32_16x16x32_bf16(a, b, acc, 0, 0, 0);
  }
  float* out = Lg + (size_t)pair * 256;
  const int col = l & 15, r0 = (l >> 4) << 2;
#pragma unroll
  for (int r = 0; r < 4; r++)
    out[(r0 + r) * 16 + col] = acc[r] * 0.03125f;
}

// ---------------- per-token small math: softmax/nps/top-4/final_attn -> g ----
// 16 tokens per block, 16 threads per token.
__global__ __launch_bounds__(256) void k_small(const float* __restrict__ Lg,
                                               const float* __restrict__ NPRE,
                                               const float* __restrict__ CB,
                                               const float* __restrict__ TW,
                                               float* __restrict__ G){
  __shared__ float npr_s[16 * 256];
  __shared__ float nps_s[16 * 256];
  __shared__ float attn_s[16 * 64];
  __shared__ float sc_s[16 * 32];
  __shared__ float tw_s[16 * 8];
  __shared__ int   sel_s[16 * 4];
  __shared__ float tkw_s[16 * 4], rmax_s[16 * 4], rsum_s[16 * 4], fa_s[16 * 8];

  const int t = threadIdx.x;
  const int loc = t >> 4, q = t & 15;
  const int tok0 = blockIdx.x * 16;
  const int tok = tok0 + loc;

  // stage NPRE for the block's 16 tokens (layout [tok][k*32+p])
  for (int i = t; i < 4096; i += 256) npr_s[i] = NPRE[(size_t)tok0 * 256 + i];
  if (q < 8) tw_s[loc * 8 + q] = TW[tok * 8 + q];

  // logits row q (q<8) -> softmax -> attn
  if (q < 8){
    const float* lrow = Lg + ((size_t)(tok >> 1) * 256) + (size_t)(tok & 1) * 136 + q * 16;
    float a[8];
    float m = -1e30f;
#pragma unroll
    for (int j = 0; j < 8; j++){ a[j] = lrow[j]; m = fmaxf(m, a[j]); }
    float s = 0.f;
#pragma unroll
    for (int j = 0; j < 8; j++){ a[j] = expf(a[j] - m); s += a[j]; }
    float inv = 1.f / s;
#pragma unroll
    for (int j = 0; j < 8; j++) attn_s[loc * 64 + q * 8 + j] = a[j] * inv;
  }
  __syncthreads();

  { // nps: thread handles column qq = q&7, patterns (q>>3)*16 .. +15
    const int qq = q & 7, p0 = (q >> 3) << 4;
    float a[8];
#pragma unroll
    for (int k = 0; k < 8; k++) a[k] = attn_s[loc * 64 + qq * 8 + k];
    const float* np = npr_s + loc * 256;
    float* npsr = nps_s + loc * 256;
    for (int p = p0; p < p0 + 16; p++){
      float acc = 0.f;
#pragma unroll
      for (int k = 0; k < 8; k++) acc += a[k] * np[k * 32 + p];
      npsr[p * 8 + qq] = acc * 0.03125f;
    }
  }
  __syncthreads();

  { // scores for p = 2q, 2q+1
    const float* npsr = nps_s + loc * 256;
#pragma unroll
    for (int pi = 0; pi < 2; pi++){
      int p = q * 2 + pi;
      float nb = 0.f;
#pragma unroll
      for (int qq = 0; qq < 8; qq++) nb += npsr[p * 8 + qq] * tw_s[loc * 8 + qq];
      sc_s[loc * 32 + p] = 0.5f * nb + 0.5f * CB[(size_t)tok * 32 + p];
    }
  }
  __syncthreads();

  if (q == 0){ // top-4 (stable: first index wins ties, like lax.top_k)
    const float* sc = sc_s + loc * 32;
    unsigned used = 0; float vals[4]; int idx[4];
    for (int kp = 0; kp < 4; kp++){
      float best = -1e30f; int bi = 0;
      for (int p = 0; p < 32; p++)
        if (!((used >> p) & 1u) && sc[p] > best){ best = sc[p]; bi = p; }
      used |= 1u << bi; vals[kp] = best; idx[kp] = bi;
    }
    float mm = vals[0], ss = 0.f, e[4];
    for (int kp = 0; kp < 4; kp++){ e[kp] = expf(vals[kp] - mm); ss += e[kp]; }
    for (int kp = 0; kp < 4; kp++){ tkw_s[loc * 4 + kp] = e[kp] / ss; sel_s[loc * 4 + kp] = idx[kp]; }
  }
  __syncthreads();

  if (q < 4){ // row softmax stats for selected patterns
    const float* npsr = nps_s + loc * 256;
    int p = sel_s[loc * 4 + q];
    float mm = -1e30f;
    for (int j = 0; j < 8; j++) mm = fmaxf(mm, npsr[p * 8 + j]);
    float ss = 0.f;
    for (int j = 0; j < 8; j++) ss += expf(npsr[p * 8 + j] - mm);
    rmax_s[loc * 4 + q] = mm; rsum_s[loc * 4 + q] = ss;
  }
  __syncthreads();

  if (q < 8){ // final_attn
    const float* npsr = nps_s + loc * 256;
    float f = 0.f;
    for (int kp = 0; kp < 4; kp++){
      int p = sel_s[loc * 4 + kp];
      f += tkw_s[loc * 4 + kp] * expf(npsr[p * 8 + q] - rmax_s[loc * 4 + kp]) / rsum_s[loc * 4 + kp];
    }
    fa_s[loc * 8 + q] = f;
  }
  __syncthreads();

  if (q < 8){ // g = fa @ attn
    float g = 0.f;
    for (int qq = 0; qq < 8; qq++) g += fa_s[loc * 8 + qq] * attn_s[loc * 64 + qq * 8 + q];
    G[(size_t)tok * 8 + q] = g;
  }
}

// ---------------- gsn[tok] = sum_k g[k] * SNB[tok*8+k]  -> bf16 --------------
__global__ __launch_bounds__(256) void k_gsn(const float* __restrict__ G,
                                             const ushort_t* __restrict__ SNB,
                                             ushort_t* __restrict__ GSN){
  const int tok = blockIdx.x, t = threadIdx.x;
  float g[8];
#pragma unroll
  for (int k = 0; k < 8; k++) g[k] = G[(size_t)tok * 8 + k];
  const ushort_t* S = SNB + (size_t)tok * 8192 + (t << 2);
  float o0 = 0, o1 = 0, o2 = 0, o3 = 0;
#pragma unroll
  for (int k = 0; k < 8; k++){
    ushort4 v = *(const ushort4*)(S + k * 1024);
    o0 += g[k] * bf2f(v.x); o1 += g[k] * bf2f(v.y);
    o2 += g[k] * bf2f(v.z); o3 += g[k] * bf2f(v.w);
  }
  uint2 pk;
  pk.x = (unsigned)f2bf(o0) | ((unsigned)f2bf(o1) << 16);
  pk.y = (unsigned)f2bf(o2) | ((unsigned)f2bf(o3) << 16);
  *((uint2*)(GSN + (size_t)tok * 1024 + (t << 2))) = pk;
}

extern "C" void kernel_launch(void* const* d_in, const int* in_sizes, int n_in,
                              void* d_out, int out_size, void* d_ws, size_t ws_size,
                              hipStream_t stream){
  (void)in_sizes; (void)n_in; (void)out_size; (void)ws_size;
  const float* x   = (const float*)d_in[0];
  const float* tw  = (const float*)d_in[3];
  const float* SN  = (const float*)d_in[4];
  const float* ctx = (const float*)d_in[5];
  const float* Wq  = (const float*)d_in[6];
  const float* bq  = (const float*)d_in[7];
  const float* Wk  = (const float*)d_in[8];
  const float* bv  = (const float*)d_in[11];
  const float* Wv  = (const float*)d_in[10];
  const float* pat = (const float*)d_in[12];
  const float* Wup = (const float*)d_in[13];
  const float* bup = (const float*)d_in[14];
  const float* Wdn = (const float*)d_in[15];
  const float* bdn = (const float*)d_in[16];
  float* out = (float*)d_out;

  char* ws = (char*)d_ws;
  size_t off = 0;
  auto alloc = [&](size_t bytes) -> char* {
    char* p = ws + off;
    off = (off + bytes + 255) & ~(size_t)255;
    return p;
  };
  ushort_t* SNB  = (ushort_t*)alloc(67108864);  // SN bf16 [32768][1024]; later aliased by H
  ushort_t* TB   = (ushort_t*)alloc(67108864);  // T bf16; later aliased by COMBINED
  float*    NPRE = (float*)alloc(4194304);      // [32768][32]
  float*    CBb  = (float*)alloc(524288);       // [4096][32]
  ushort_t* GSN  = (ushort_t*)alloc(8388608);   // [4096][1024] bf16
  ushort_t* CTXB = (ushort_t*)alloc(8388608);
  ushort_t* PATB = (ushort_t*)alloc(65536);
  ushort_t* WVB  = (ushort_t*)alloc(2097152);
  ushort_t* WUPB = (ushort_t*)alloc(8388608);
  ushort_t* WDNB = (ushort_t*)alloc(8388608);
  ushort_t* ATB  = (ushort_t*)alloc(2097152);
  ushort_t* WKTB = (ushort_t*)alloc(2097152);
  ushort_t* WQTB = (ushort_t*)alloc(2097152);
  ushort_t* PVB  = (ushort_t*)alloc(65536);
  float*    WVEC = (float*)alloc(4096);
  float*    PBv  = (float*)alloc(128);
  float*    Lg   = (float*)alloc(2097152);      // [2048 pairs][256] fp32 logits
  float*    G    = (float*)alloc(131072);       // [4096][8] fp32
  ushort_t* H    = SNB;   // 32MB alias (SNB dead by FFN time)
  ushort_t* CMB  = TB;    // 8MB alias (T dead after k_logits)

  // dtype converts / transposes
  k_cvt_bf16<<<32768, 256, 0, stream>>>(SN,  SNB,  8388608);
  k_cvt_bf16<<<4096,  256, 0, stream>>>(ctx, CTXB, 1048576);
  k_cvt_bf16<<<32,    256, 0, stream>>>(pat, PATB, 8192);
  k_cvt_bf16<<<1024,  256, 0, stream>>>(Wv,  WVB,  262144);
  k_cvt_bf16<<<4096,  256, 0, stream>>>(Wup, WUPB, 1048576);
  k_cvt_bf16<<<4096,  256, 0, stream>>>(Wdn, WDNB, 1048576);
  k_transpose_cvt<<<dim3(32, 32), 256, 0, stream>>>(Wq, WQTB);
  k_transpose_cvt<<<dim3(32, 32), 256, 0, stream>>>(Wk, WKTB);
  k_wvec<<<4, 256, 0, stream>>>(bq, Wk, WVEC);
  k_pb<<<1, 256, 0, stream>>>(pat, bv, PBv);
  k_pv<<<dim3(4, 32), 256, 0, stream>>>(pat, Wv, PVB);

  // At[d'][d] = sum_e Wk[e][d']*Wq[e][d]
  k_gemm_bt<0><<<dim3(8, 8), 256, 0, stream>>>(WKTB, WQTB, ATB, nullptr, nullptr, 1024, 1024, 1024);
  // T = SN @ At^T + wvec  (wvec folds the bq-row bias; row-constant terms cancel in softmax)
  k_gemm_bt<1><<<dim3(8, 256), 256, 0, stream>>>(SNB, ATB, TB, WVEC, nullptr, 32768, 1024, 1024);
  // NPRE[m][p] = SN[m] . PV[p] + pb[p]
  k_gemm_n32<true><<<256, 256, 0, stream>>>(SNB, PVB, NPRE, PBv, 32768, 1024);
  // CB[tok][p] = context[tok] . pattern[p]
  k_gemm_n32<false><<<32, 256, 0, stream>>>(CTXB, PATB, CBb, nullptr, 4096, 1024);
  // batched per-token-pair logits via MFMA straight from global
  k_logits<<<512, 256, 0, stream>>>(TB, SNB, Lg);
  // per-token softmax / nps / top-4 / final_attn -> g
  k_small<<<256, 256, 0, stream>>>(Lg, NPRE, CBb, tw, G);
  // gsn = g @ SN (bf16 rows)
  k_gsn<<<4096, 256, 0, stream>>>(G, SNB, GSN);
  // combined = gsn @ Wv^T + bv + x   (bf16)
  k_gemm_bt<2><<<dim3(8, 32), 256, 0, stream>>>(GSN, WVB, CMB, bv, x, 4096, 1024, 1024);
  // H = gelu(combined @ Wup^T + bup) (bf16)
  k_gemm_bt<3><<<dim3(32, 32), 256, 0, stream>>>(CMB, WUPB, H, bup, nullptr, 4096, 4096, 1024);
  // out = H @ Wdown^T + bdown        (fp32)
  k_gemm_bt<4><<<dim3(8, 32), 256, 0, stream>>>(H, WDNB, out, bdn, nullptr, 4096, 1024, 4096);
}

// Round 3
// 675.195 us; speedup vs baseline: 1.3122x; 1.1310x over previous
//
#include <hip/hip_runtime.h>
#include <math.h>

// B=2,S=2048 -> NT=4096 tokens; K=8, D=1024, P=32, KP=4, DFF=4096
typedef unsigned short ushort_t;
typedef __attribute__((ext_vector_type(8))) short short8;
typedef __attribute__((ext_vector_type(4))) float floatx4;

static __device__ __forceinline__ float bf2f(ushort_t h){
  return __uint_as_float(((unsigned int)h) << 16);
}
static __device__ __forceinline__ ushort_t f2bf(float f){
  unsigned int u = __float_as_uint(f);
  unsigned int r = u + 0x7FFFu + ((u >> 16) & 1u);   // round-to-nearest-even
  return (ushort_t)(r >> 16);
}
static __device__ __forceinline__ void unpack8(uint4 u, float* f){
  f[0] = __uint_as_float(u.x << 16); f[1] = __uint_as_float(u.x & 0xffff0000u);
  f[2] = __uint_as_float(u.y << 16); f[3] = __uint_as_float(u.y & 0xffff0000u);
  f[4] = __uint_as_float(u.z << 16); f[5] = __uint_as_float(u.z & 0xffff0000u);
  f[6] = __uint_as_float(u.w << 16); f[7] = __uint_as_float(u.w & 0xffff0000u);
}
static __device__ __forceinline__ uint4 pack8(const float* f){
  uint4 u;
  u.x = (unsigned)f2bf(f[0]) | ((unsigned)f2bf(f[1]) << 16);
  u.y = (unsigned)f2bf(f[2]) | ((unsigned)f2bf(f[3]) << 16);
  u.z = (unsigned)f2bf(f[4]) | ((unsigned)f2bf(f[5]) << 16);
  u.w = (unsigned)f2bf(f[6]) | ((unsigned)f2bf(f[7]) << 16);
  return u;
}

static __device__ __forceinline__ void gload16(const void* g, void* l){
  __builtin_amdgcn_global_load_lds((const __attribute__((address_space(1))) void*)g,
                                   (__attribute__((address_space(3))) void*)l, 16, 0, 0);
}

// ---------------- merged fp32 -> bf16 converts (6 tensors, one launch) --------
__global__ __launch_bounds__(256) void k_cvt_multi(
    const float* __restrict__ s0, ushort_t* __restrict__ d0, int e0,
    const float* __restrict__ s1, ushort_t* __restrict__ d1, int e1,
    const float* __restrict__ s2, ushort_t* __restrict__ d2, int e2,
    const float* __restrict__ s3, ushort_t* __restrict__ d3, int e3,
    const float* __restrict__ s4, ushort_t* __restrict__ d4, int e4,
    const float* __restrict__ s5, ushort_t* __restrict__ d5, int e5){
  int i = blockIdx.x * 256 + threadIdx.x;
  const float* s; ushort_t* d; int b;
  if      (i < e0){ s = s0; d = d0; b = 0;  }
  else if (i < e1){ s = s1; d = d1; b = e0; }
  else if (i < e2){ s = s2; d = d2; b = e1; }
  else if (i < e3){ s = s3; d = d3; b = e2; }
  else if (i < e4){ s = s4; d = d4; b = e3; }
  else if (i < e5){ s = s5; d = d5; b = e4; }
  else return;
  int j = i - b;
  float4 v = ((const float4*)s)[j];
  unsigned long long p = (unsigned long long)f2bf(v.x)
                       | ((unsigned long long)f2bf(v.y) << 16)
                       | ((unsigned long long)f2bf(v.z) << 32)
                       | ((unsigned long long)f2bf(v.w) << 48);
  ((unsigned long long*)d)[j] = p;
}

// ---------------- 3x 1024x1024 transpose with bf16 convert (one launch) -------
__global__ __launch_bounds__(256) void k_transpose3(const float* __restrict__ s0, ushort_t* __restrict__ d0,
                                                    const float* __restrict__ s1, ushort_t* __restrict__ d1,
                                                    const float* __restrict__ s2, ushort_t* __restrict__ d2){
  __shared__ float tile[32][33];
  const float* in; ushort_t* out;
  if      (blockIdx.z == 0){ in = s0; out = d0; }
  else if (blockIdx.z == 1){ in = s1; out = d1; }
  else                     { in = s2; out = d2; }
  int bx = blockIdx.x * 32, by = blockIdx.y * 32;
  int tx = threadIdx.x & 31, ty = threadIdx.x >> 5;   // ty 0..7
  for (int i = 0; i < 32; i += 8)
    tile[ty + i][tx] = in[(size_t)(by + ty + i) * 1024 + bx + tx];
  __syncthreads();
  for (int i = 0; i < 32; i += 8)
    out[(size_t)(bx + ty + i) * 1024 + by + tx] = f2bf(tile[tx][ty + i]);
}

// wvec[d] = sum_e bq[e]*Wk[e][d] = WkT_row[d] . bq   — wave per d (grid 256)
__global__ __launch_bounds__(256) void k_wvec2(const float* __restrict__ bq,
                                               const ushort_t* __restrict__ WKT,
                                               float* __restrict__ wv){
  int d = (blockIdx.x << 2) + (threadIdx.x >> 6);
  int l = threadIdx.x & 63;
  const uint4* row = (const uint4*)(WKT + (size_t)d * 1024 + (l << 4));
  const float4* b4 = (const float4*)(bq + (l << 4));
  float w[16], bb[16];
  unpack8(row[0], w); unpack8(row[1], w + 8);
#pragma unroll
  for (int i = 0; i < 4; i++){
    float4 v = b4[i];
    bb[i*4] = v.x; bb[i*4+1] = v.y; bb[i*4+2] = v.z; bb[i*4+3] = v.w;
  }
  float a = 0.f;
#pragma unroll
  for (int i = 0; i < 16; i++) a += w[i] * bb[i];
#pragma unroll
  for (int s = 1; s < 64; s <<= 1) a += __shfl_xor(a, s);
  if (l == 0) wv[d] = a;
}

// pb[p] = pattern[p] . bv — wave per p (grid 8)
__global__ __launch_bounds__(256) void k_pb2(const float* __restrict__ pat,
                                             const float* __restrict__ bv,
                                             float* __restrict__ pb){
  int p = (blockIdx.x << 2) + (threadIdx.x >> 6);
  int l = threadIdx.x & 63;
  const float4* pr = (const float4*)(pat + p * 1024) + l;
  const float4* b4 = (const float4*)bv + l;
  float a = 0.f;
#pragma unroll
  for (int i = 0; i < 4; i++){
    float4 x = pr[i * 64], y = b4[i * 64];
    a += x.x * y.x + x.y * y.y + x.z * y.z + x.w * y.w;
  }
#pragma unroll
  for (int s = 1; s < 64; s <<= 1) a += __shfl_xor(a, s);
  if (l == 0) pb[p] = a;
}

// PV[p][d] = pat_row[p] . WvT_row[d] — wave per d, loop p (grid 256)
__global__ __launch_bounds__(256) void k_pv2(const ushort_t* __restrict__ WVT,
                                             const ushort_t* __restrict__ PATB,
                                             ushort_t* __restrict__ PVB){
  int d = (blockIdx.x << 2) + (threadIdx.x >> 6);
  int l = threadIdx.x & 63;
  const uint4* wr = (const uint4*)(WVT + (size_t)d * 1024 + (l << 4));
  float w[16];
  unpack8(wr[0], w); unpack8(wr[1], w + 8);
  for (int p = 0; p < 32; p++){
    const uint4* pr = (const uint4*)(PATB + p * 1024 + (l << 4));
    float pw[16];
    unpack8(pr[0], pw); unpack8(pr[1], pw + 8);
    float a = 0.f;
#pragma unroll
    for (int i = 0; i < 16; i++) a += w[i] * pw[i];
#pragma unroll
    for (int s = 1; s < 64; s <<= 1) a += __shfl_xor(a, s);
    if (l == 0) PVB[p * 1024 + d] = f2bf(a);
  }
}

// ---------------- main bf16 GEMM: out[m][n] = sum_k A[m][k]*B[n][k] ----------------
// 1D grid with XCD-aware swizzle: id = xcd + 8*(n + GN*mq); m-tile = mq*8+xcd.
// All GN n-blocks of one m-tile land consecutively on ONE XCD -> A-tile fetched
// once into that XCD's L2. Requires gridM % 8 == 0.
// MODE 0: bf16(acc)  1: bf16(acc+bias)  2: bf16(acc+bias+Xadd)  3: bf16(gelu(acc+bias))  4: fp32(acc+bias)
template<int MODE, int GN>
__global__ __launch_bounds__(256) void k_gemm_bt(const ushort_t* __restrict__ A,
                                                 const ushort_t* __restrict__ B,
                                                 void* __restrict__ C,
                                                 const float* __restrict__ bias,
                                                 const float* __restrict__ Xadd,
                                                 int M, int N, int K){
  (void)M;
  __shared__ ushort_t As[128 * 32];
  __shared__ ushort_t Bs[128 * 32];
  const int tid = threadIdx.x;
  const int w = tid >> 6, l = tid & 63;
  const int id = blockIdx.x;
  const int xcd = id & 7;
  const int t2 = id >> 3;
  const int nt = t2 % GN;
  const int mt = ((t2 / GN) << 3) + xcd;
  const int m0 = mt << 7, n0 = nt << 7;
  const int wm = (w >> 1) << 6, wn = (w & 1) << 6;
  const int rA = (w << 4) + (l >> 2);   // staging row 0..63 (+64 second round)
  const int cA = (l & 3) << 3;          // staging col in elems
  const int fr = l & 15, fq = l >> 4;

  floatx4 acc[4][4];
#pragma unroll
  for (int i = 0; i < 4; i++)
#pragma unroll
    for (int j = 0; j < 4; j++) acc[i][j] = (floatx4)0.0f;

  const ushort_t* Ab = A + (size_t)(m0 + rA) * K + cA;
  const ushort_t* Bb = B + (size_t)(n0 + rA) * K + cA;
  const size_t row64 = (size_t)64 * K;
  ushort_t* Asw = As + (w << 9);
  ushort_t* Bsw = Bs + (w << 9);

  for (int k0 = 0; k0 < K; k0 += 32){
    __syncthreads();
    gload16(Ab + k0, Asw);
    gload16(Ab + row64 + k0, Asw + 2048);
    gload16(Bb + k0, Bsw);
    gload16(Bb + row64 + k0, Bsw + 2048);
    __syncthreads();
    short8 af[4], bg[4];
#pragma unroll
    for (int i = 0; i < 4; i++){
      af[i] = *(const short8*)(As + ((wm + (i << 4) + fr) << 5) + (fq << 3));
      bg[i] = *(const short8*)(Bs + ((wn + (i << 4) + fr) << 5) + (fq << 3));
    }
#pragma unroll
    for (int i = 0; i < 4; i++)
#pragma unroll
      for (int j = 0; j < 4; j++)
        acc[i][j] = __builtin_amdgcn_mfma_f32_16x16x32_bf16(af[i], bg[j], acc[i][j], 0, 0, 0);
  }

#pragma unroll
  for (int i = 0; i < 4; i++){
    int row = m0 + wm + (i << 4) + (fq << 2);
#pragma unroll
    for (int j = 0; j < 4; j++){
      int col = n0 + wn + (j << 4) + fr;
      float b = (MODE >= 1) ? bias[col] : 0.0f;
#pragma unroll
      for (int r = 0; r < 4; r++){
        float v = acc[i][j][r] + b;
        size_t idx = (size_t)(row + r) * N + col;
        if (MODE == 2) v += Xadd[idx];
        if (MODE == 3) v = 0.5f * v * (1.0f + erff(v * 0.70710678118654752f));
        if (MODE == 4) ((float*)C)[idx] = v;
        else           ((ushort_t*)C)[idx] = f2bf(v);
      }
    }
  }
}

// ---------------- skinny N=32 GEMM: C[m][p] = sum_k A[m][k]*B[p][k] (+ bvec[p]) ----------------
template<bool ADDB>
__global__ __launch_bounds__(256) void k_gemm_n32(const ushort_t* __restrict__ A,
                                                  const ushort_t* __restrict__ B,
                                                  float* __restrict__ C,
                                                  const float* __restrict__ bvec,
                                                  int M, int K){
  (void)M;
  __shared__ ushort_t As[128 * 32];
  __shared__ ushort_t Bs[32 * 32];
  const int tid = threadIdx.x;
  const int w = tid >> 6, l = tid & 63;
  const int m0 = blockIdx.x << 7;
  const int rA = (w << 4) + (l >> 2);
  const int cA = (l & 3) << 3;
  const int fr = l & 15, fq = l >> 4;

  floatx4 acc[2][2];
#pragma unroll
  for (int i = 0; i < 2; i++)
#pragma unroll
    for (int j = 0; j < 2; j++) acc[i][j] = (floatx4)0.0f;

  const ushort_t* Ab = A + (size_t)(m0 + rA) * K + cA;
  const ushort_t* Bb = B + (size_t)rA * K + cA;    // valid rows only for w<2
  const size_t row64 = (size_t)64 * K;

  for (int k0 = 0; k0 < K; k0 += 32){
    __syncthreads();
    gload16(Ab + k0, As + (w << 9));
    gload16(Ab + row64 + k0, As + 2048 + (w << 9));
    if (w < 2) gload16(Bb + k0, Bs + (w << 9));
    __syncthreads();
    short8 af[2], bg[2];
#pragma unroll
    for (int i = 0; i < 2; i++)
      af[i] = *(const short8*)(As + (((w << 5) + (i << 4) + fr) << 5) + (fq << 3));
#pragma unroll
    for (int j = 0; j < 2; j++)
      bg[j] = *(const short8*)(Bs + (((j << 4) + fr) << 5) + (fq << 3));
#pragma unroll
    for (int i = 0; i < 2; i++)
#pragma unroll
      for (int j = 0; j < 2; j++)
        acc[i][j] = __builtin_amdgcn_mfma_f32_16x16x32_bf16(af[i], bg[j], acc[i][j], 0, 0, 0);
  }

#pragma unroll
  for (int i = 0; i < 2; i++){
    int row = m0 + (w << 5) + (i << 4) + (fq << 2);
#pragma unroll
    for (int j = 0; j < 2; j++){
      int col = (j << 4) + fr;
      float b = ADDB ? bvec[col] : 0.0f;
#pragma unroll
      for (int r = 0; r < 4; r++)
        C[(size_t)(row + r) * 32 + col] = acc[i][j][r] + b;
    }
  }
}

// ---------------- fused attention: logits(MFMA) -> softmax/nps/top-4 -> gsn ---
// block = 4 waves = 4 token-pairs = 8 tokens.
__global__ __launch_bounds__(256) void k_attn(const ushort_t* __restrict__ T,
                                              const ushort_t* __restrict__ SNB,
                                              const float* __restrict__ NPRE,
                                              const float* __restrict__ CB,
                                              const float* __restrict__ TW,
                                              ushort_t* __restrict__ GSN){
  __shared__ float logit_s[4 * 256];
  __shared__ float attn_s[8 * 64];
  __shared__ float npr_s[8 * 256];
  __shared__ float nps_s[8 * 256];
  __shared__ float sc_s[8 * 32];
  __shared__ float tw_s[8 * 8];
  __shared__ int   sel_s[8 * 4];
  __shared__ float tkw_s[8 * 4], rmax_s[8 * 4], rsum_s[8 * 4], fa_s[8 * 8], g_s[8 * 8];

  const int t = threadIdx.x;
  const int w = t >> 6, l = t & 63;
  const int tok0 = blockIdx.x << 3;
  const int pair = (blockIdx.x << 2) + w;

  { // MFMA logits for this wave's pair (fragments straight from global)
    const size_t rbase = (size_t)pair * 16 + (l & 15);
    const int ko = (l >> 4) << 3;
    const ushort_t* Ap = T   + rbase * 1024 + ko;
    const ushort_t* Bp = SNB + rbase * 1024 + ko;
    floatx4 acc = (floatx4)0.0f;
#pragma unroll 4
    for (int k0 = 0; k0 < 1024; k0 += 32){
      short8 a = *(const short8*)(Ap + k0);
      short8 b = *(const short8*)(Bp + k0);
      acc = __builtin_amdgcn_mfma_f32_16x16x32_bf16(a, b, acc, 0, 0, 0);
    }
    const int col = l & 15, r0 = (l >> 4) << 2;
#pragma unroll
    for (int r = 0; r < 4; r++)
      logit_s[(w << 8) + (r0 + r) * 16 + col] = acc[r] * 0.03125f;
  }
  { // stage NPRE (8 tokens x 256) + tw
#pragma unroll
    for (int i = 0; i < 8; i++)
      npr_s[(i << 8) + t] = NPRE[((size_t)tok0 << 8) + (i << 8) + t];
    if (t < 64) tw_s[t] = TW[(tok0 << 3) + t];
  }
  __syncthreads();

  const int loc = t >> 5, q = t & 31;    // token-in-block, lane-in-token-group
  if (q < 8){ // softmax of logit row q for token loc
    const float* lrow = logit_s + ((loc >> 1) << 8) + (loc & 1) * 136 + q * 16;
    float a[8]; float m = -1e30f;
#pragma unroll
    for (int j = 0; j < 8; j++){ a[j] = lrow[j]; m = fmaxf(m, a[j]); }
    float s = 0.f;
#pragma unroll
    for (int j = 0; j < 8; j++){ a[j] = expf(a[j] - m); s += a[j]; }
    float inv = 1.f / s;
#pragma unroll
    for (int j = 0; j < 8; j++) attn_s[(loc << 6) + q * 8 + j] = a[j] * inv;
  }
  __syncthreads();

  { // nps: column qq = q&7, patterns (q>>3)*8..+7
    const int qq = q & 7, p0 = (q >> 3) << 3;
    float a[8];
#pragma unroll
    for (int k = 0; k < 8; k++) a[k] = attn_s[(loc << 6) + qq * 8 + k];
    const float* np = npr_s + (loc << 8);
    float* npsr = nps_s + (loc << 8);
    for (int p = p0; p < p0 + 8; p++){
      float acc = 0.f;
#pragma unroll
      for (int k = 0; k < 8; k++) acc += a[k] * np[k * 32 + p];
      npsr[p * 8 + qq] = acc * 0.03125f;
    }
  }
  __syncthreads();

  { // scores, p = q
    const float* npsr = nps_s + (loc << 8);
    float nb = 0.f;
#pragma unroll
    for (int qq = 0; qq < 8; qq++) nb += npsr[q * 8 + qq] * tw_s[(loc << 3) + qq];
    sc_s[(loc << 5) + q] = 0.5f * nb + 0.5f * CB[((size_t)(tok0 + loc) << 5) + q];
  }
  __syncthreads();

  if (q == 0){ // top-4 (stable: first index wins ties, like lax.top_k)
    const float* sc = sc_s + (loc << 5);
    unsigned used = 0; float vals[4]; int idx[4];
    for (int kp = 0; kp < 4; kp++){
      float best = -1e30f; int bi = 0;
      for (int p = 0; p < 32; p++)
        if (!((used >> p) & 1u) && sc[p] > best){ best = sc[p]; bi = p; }
      used |= 1u << bi; vals[kp] = best; idx[kp] = bi;
    }
    float mm = vals[0], ss = 0.f, e[4];
    for (int kp = 0; kp < 4; kp++){ e[kp] = expf(vals[kp] - mm); ss += e[kp]; }
    for (int kp = 0; kp < 4; kp++){ tkw_s[(loc << 2) + kp] = e[kp] / ss; sel_s[(loc << 2) + kp] = idx[kp]; }
  }
  __syncthreads();

  if (q < 4){ // row softmax stats for selected patterns
    const float* npsr = nps_s + (loc << 8);
    int p = sel_s[(loc << 2) + q];
    float mm = -1e30f;
    for (int j = 0; j < 8; j++) mm = fmaxf(mm, npsr[p * 8 + j]);
    float ss = 0.f;
    for (int j = 0; j < 8; j++) ss += expf(npsr[p * 8 + j] - mm);
    rmax_s[(loc << 2) + q] = mm; rsum_s[(loc << 2) + q] = ss;
  }
  __syncthreads();

  if (q < 8){ // final_attn
    const float* npsr = nps_s + (loc << 8);
    float f = 0.f;
    for (int kp = 0; kp < 4; kp++){
      int p = sel_s[(loc << 2) + kp];
      f += tkw_s[(loc << 2) + kp] * expf(npsr[p * 8 + q] - rmax_s[(loc << 2) + kp]) / rsum_s[(loc << 2) + kp];
    }
    fa_s[(loc << 3) + q] = f;
  }
  __syncthreads();

  if (q < 8){ // g = fa @ attn
    float g = 0.f;
    for (int qq = 0; qq < 8; qq++) g += fa_s[(loc << 3) + qq] * attn_s[(loc << 6) + qq * 8 + q];
    g_s[(loc << 3) + q] = g;
  }
  __syncthreads();

  // gsn: each wave handles its pair's 2 tokens; SNB rows are L1/L2-hot
  for (int tl = 0; tl < 2; tl++){
    const int tkl = (w << 1) + tl;
    const size_t tok = (size_t)tok0 + tkl;
    float o[16];
#pragma unroll
    for (int i = 0; i < 16; i++) o[i] = 0.f;
#pragma unroll
    for (int k = 0; k < 8; k++){
      float gk = g_s[(tkl << 3) + k];
      const uint4* src = (const uint4*)(SNB + ((tok << 3) + k) * 1024 + (l << 4));
      float f0[8], f1[8];
      unpack8(src[0], f0);
      unpack8(src[1], f1);
#pragma unroll
      for (int i = 0; i < 8; i++){ o[i] += gk * f0[i]; o[8 + i] += gk * f1[i]; }
    }
    uint4* dst = (uint4*)(GSN + tok * 1024 + (l << 4));
    dst[0] = pack8(o);
    dst[1] = pack8(o + 8);
  }
}

extern "C" void kernel_launch(void* const* d_in, const int* in_sizes, int n_in,
                              void* d_out, int out_size, void* d_ws, size_t ws_size,
                              hipStream_t stream){
  (void)in_sizes; (void)n_in; (void)out_size; (void)ws_size;
  const float* x   = (const float*)d_in[0];
  const float* tw  = (const float*)d_in[3];
  const float* SN  = (const float*)d_in[4];
  const float* ctx = (const float*)d_in[5];
  const float* Wq  = (const float*)d_in[6];
  const float* bq  = (const float*)d_in[7];
  const float* Wk  = (const float*)d_in[8];
  const float* Wv  = (const float*)d_in[10];
  const float* bv  = (const float*)d_in[11];
  const float* pat = (const float*)d_in[12];
  const float* Wup = (const float*)d_in[13];
  const float* bup = (const float*)d_in[14];
  const float* Wdn = (const float*)d_in[15];
  const float* bdn = (const float*)d_in[16];
  float* out = (float*)d_out;

  char* ws = (char*)d_ws;
  size_t off = 0;
  auto alloc = [&](size_t bytes) -> char* {
    char* p = ws + off;
    off = (off + bytes + 255) & ~(size_t)255;
    return p;
  };
  ushort_t* SNB  = (ushort_t*)alloc(67108864);  // SN bf16 [32768][1024]; later aliased by H
  ushort_t* TB   = (ushort_t*)alloc(67108864);  // T bf16; later aliased by COMBINED
  float*    NPRE = (float*)alloc(4194304);      // [32768][32]
  float*    CBb  = (float*)alloc(524288);       // [4096][32]
  ushort_t* GSN  = (ushort_t*)alloc(8388608);   // [4096][1024] bf16
  ushort_t* CTXB = (ushort_t*)alloc(8388608);
  ushort_t* PATB = (ushort_t*)alloc(65536);
  ushort_t* WVB  = (ushort_t*)alloc(2097152);
  ushort_t* WUPB = (ushort_t*)alloc(8388608);
  ushort_t* WDNB = (ushort_t*)alloc(8388608);
  ushort_t* ATB  = (ushort_t*)alloc(2097152);
  ushort_t* WKTB = (ushort_t*)alloc(2097152);
  ushort_t* WQTB = (ushort_t*)alloc(2097152);
  ushort_t* WVTB = (ushort_t*)alloc(2097152);
  ushort_t* PVB  = (ushort_t*)alloc(65536);
  float*    WVEC = (float*)alloc(4096);
  float*    PBv  = (float*)alloc(128);
  ushort_t* H    = SNB;   // 32MB alias (SNB dead by FFN time)
  ushort_t* CMB  = TB;    // 8MB alias (T dead after k_attn)

  // converts (one launch) + transposes (one launch)
  const int e0 = 8388608, e1 = e0 + 1048576, e2 = e1 + 8192,
            e3 = e2 + 262144, e4 = e3 + 1048576, e5 = e4 + 1048576;
  k_cvt_multi<<<(e5 + 255) / 256, 256, 0, stream>>>(
      SN, SNB, e0, ctx, CTXB, e1, pat, PATB, e2,
      Wv, WVB, e3, Wup, WUPB, e4, Wdn, WDNB, e5);
  k_transpose3<<<dim3(32, 32, 3), 256, 0, stream>>>(Wq, WQTB, Wk, WKTB, Wv, WVTB);
  k_wvec2<<<256, 256, 0, stream>>>(bq, WKTB, WVEC);
  k_pb2<<<8, 256, 0, stream>>>(pat, bv, PBv);
  k_pv2<<<256, 256, 0, stream>>>(WVTB, PATB, PVB);

  // At[d'][d] = sum_e Wk[e][d']*Wq[e][d]
  k_gemm_bt<0, 8><<<64, 256, 0, stream>>>(WKTB, WQTB, ATB, nullptr, nullptr, 1024, 1024, 1024);
  // T = SN @ At^T + wvec  (wvec folds the bq bias; row-constant terms cancel in softmax)
  k_gemm_bt<1, 8><<<2048, 256, 0, stream>>>(SNB, ATB, TB, WVEC, nullptr, 32768, 1024, 1024);
  // NPRE[m][p] = SN[m] . PV[p] + pb[p]
  k_gemm_n32<true><<<256, 256, 0, stream>>>(SNB, PVB, NPRE, PBv, 32768, 1024);
  // CB[tok][p] = context[tok] . pattern[p]
  k_gemm_n32<false><<<32, 256, 0, stream>>>(CTXB, PATB, CBb, nullptr, 4096, 1024);
  // fused: logits (MFMA) -> softmax/nps/top-4/final_attn -> gsn
  k_attn<<<512, 256, 0, stream>>>(TB, SNB, NPRE, CBb, tw, GSN);
  // combined = gsn @ Wv^T + bv + x   (bf16)
  k_gemm_bt<2, 8><<<256, 256, 0, stream>>>(GSN, WVB, CMB, bv, x, 4096, 1024, 1024);
  // H = gelu(combined @ Wup^T + bup) (bf16)
  k_gemm_bt<3, 32><<<1024, 256, 0, stream>>>(CMB, WUPB, H, bup, nullptr, 4096, 4096, 1024);
  // out = H @ Wdown^T + bdown        (fp32)
  k_gemm_bt<4, 8><<<256, 256, 0, stream>>>(H, WDNB, out, bdn, nullptr, 4096, 1024, 4096);
}

// Round 4
// 630.542 us; speedup vs baseline: 1.4052x; 1.0708x over previous
//
#include <hip/hip_runtime.h>
#include <math.h>

// B=2,S=2048 -> NT=4096 tokens; K=8, D=1024, P=32, KP=4, DFF=4096
typedef unsigned short ushort_t;
typedef __attribute__((ext_vector_type(8))) short short8;
typedef __attribute__((ext_vector_type(4))) float floatx4;

static __device__ __forceinline__ ushort_t f2bf(float f){
  unsigned int u = __float_as_uint(f);
  unsigned int r = u + 0x7FFFu + ((u >> 16) & 1u);   // round-to-nearest-even
  return (ushort_t)(r >> 16);
}
static __device__ __forceinline__ void unpack8(uint4 u, float* f){
  f[0] = __uint_as_float(u.x << 16); f[1] = __uint_as_float(u.x & 0xffff0000u);
  f[2] = __uint_as_float(u.y << 16); f[3] = __uint_as_float(u.y & 0xffff0000u);
  f[4] = __uint_as_float(u.z << 16); f[5] = __uint_as_float(u.z & 0xffff0000u);
  f[6] = __uint_as_float(u.w << 16); f[7] = __uint_as_float(u.w & 0xffff0000u);
}
static __device__ __forceinline__ uint4 pack8(const float* f){
  uint4 u;
  u.x = (unsigned)f2bf(f[0]) | ((unsigned)f2bf(f[1]) << 16);
  u.y = (unsigned)f2bf(f[2]) | ((unsigned)f2bf(f[3]) << 16);
  u.z = (unsigned)f2bf(f[4]) | ((unsigned)f2bf(f[5]) << 16);
  u.w = (unsigned)f2bf(f[6]) | ((unsigned)f2bf(f[7]) << 16);
  return u;
}

static __device__ __forceinline__ void gload16(const void* g, void* l){
  __builtin_amdgcn_global_load_lds((const __attribute__((address_space(1))) void*)g,
                                   (__attribute__((address_space(3))) void*)l, 16, 0, 0);
}

// ---------------- merged fp32 -> bf16 converts (6 tensors, one launch) --------
__global__ __launch_bounds__(256) void k_cvt_multi(
    const float* __restrict__ s0, ushort_t* __restrict__ d0, int e0,
    const float* __restrict__ s1, ushort_t* __restrict__ d1, int e1,
    const float* __restrict__ s2, ushort_t* __restrict__ d2, int e2,
    const float* __restrict__ s3, ushort_t* __restrict__ d3, int e3,
    const float* __restrict__ s4, ushort_t* __restrict__ d4, int e4,
    const float* __restrict__ s5, ushort_t* __restrict__ d5, int e5){
  int i = blockIdx.x * 256 + threadIdx.x;
  const float* s; ushort_t* d; int b;
  if      (i < e0){ s = s0; d = d0; b = 0;  }
  else if (i < e1){ s = s1; d = d1; b = e0; }
  else if (i < e2){ s = s2; d = d2; b = e1; }
  else if (i < e3){ s = s3; d = d3; b = e2; }
  else if (i < e4){ s = s4; d = d4; b = e3; }
  else if (i < e5){ s = s5; d = d5; b = e4; }
  else return;
  int j = i - b;
  float4 v = ((const float4*)s)[j];
  unsigned long long p = (unsigned long long)f2bf(v.x)
                       | ((unsigned long long)f2bf(v.y) << 16)
                       | ((unsigned long long)f2bf(v.z) << 32)
                       | ((unsigned long long)f2bf(v.w) << 48);
  ((unsigned long long*)d)[j] = p;
}

// ---------------- 3x 1024x1024 transpose with bf16 convert (one launch) -------
__global__ __launch_bounds__(256) void k_transpose3(const float* __restrict__ s0, ushort_t* __restrict__ d0,
                                                    const float* __restrict__ s1, ushort_t* __restrict__ d1,
                                                    const float* __restrict__ s2, ushort_t* __restrict__ d2){
  __shared__ float tile[32][33];
  const float* in; ushort_t* out;
  if      (blockIdx.z == 0){ in = s0; out = d0; }
  else if (blockIdx.z == 1){ in = s1; out = d1; }
  else                     { in = s2; out = d2; }
  int bx = blockIdx.x * 32, by = blockIdx.y * 32;
  int tx = threadIdx.x & 31, ty = threadIdx.x >> 5;   // ty 0..7
  for (int i = 0; i < 32; i += 8)
    tile[ty + i][tx] = in[(size_t)(by + ty + i) * 1024 + bx + tx];
  __syncthreads();
  for (int i = 0; i < 32; i += 8)
    out[(size_t)(bx + ty + i) * 1024 + by + tx] = f2bf(tile[tx][ty + i]);
}

// ---------------- merged prep: wvec (256 blk) | pb (8 blk) | PV (256 blk) -----
// wvec[d] = WkT_row[d].bq ; pb[p] = pat[p].bv ; PV[p][d] = pat_row[p].WvT_row[d]
__global__ __launch_bounds__(256) void k_prep(const float* __restrict__ bq,
                                              const ushort_t* __restrict__ WKT,
                                              float* __restrict__ wv,
                                              const float* __restrict__ pat,
                                              const float* __restrict__ bv,
                                              float* __restrict__ pb,
                                              const ushort_t* __restrict__ WVT,
                                              const ushort_t* __restrict__ PATB,
                                              ushort_t* __restrict__ PVB){
  const int bid = blockIdx.x;
  const int l = threadIdx.x & 63;
  if (bid < 256){            // wvec
    int d = (bid << 2) + (threadIdx.x >> 6);
    const uint4* row = (const uint4*)(WKT + (size_t)d * 1024 + (l << 4));
    const float4* b4 = (const float4*)(bq + (l << 4));
    float w[16], bb[16];
    unpack8(row[0], w); unpack8(row[1], w + 8);
#pragma unroll
    for (int i = 0; i < 4; i++){
      float4 v = b4[i];
      bb[i*4] = v.x; bb[i*4+1] = v.y; bb[i*4+2] = v.z; bb[i*4+3] = v.w;
    }
    float a = 0.f;
#pragma unroll
    for (int i = 0; i < 16; i++) a += w[i] * bb[i];
#pragma unroll
    for (int s = 1; s < 64; s <<= 1) a += __shfl_xor(a, s);
    if (l == 0) wv[d] = a;
  } else if (bid < 264){     // pb
    int p = ((bid - 256) << 2) + (threadIdx.x >> 6);
    const float4* pr = (const float4*)(pat + p * 1024) + l;
    const float4* b4 = (const float4*)bv + l;
    float a = 0.f;
#pragma unroll
    for (int i = 0; i < 4; i++){
      float4 x = pr[i * 64], y = b4[i * 64];
      a += x.x * y.x + x.y * y.y + x.z * y.z + x.w * y.w;
    }
#pragma unroll
    for (int s = 1; s < 64; s <<= 1) a += __shfl_xor(a, s);
    if (l == 0) pb[p] = a;
  } else {                   // PV
    int d = ((bid - 264) << 2) + (threadIdx.x >> 6);
    const uint4* wr = (const uint4*)(WVT + (size_t)d * 1024 + (l << 4));
    float w[16];
    unpack8(wr[0], w); unpack8(wr[1], w + 8);
    for (int p = 0; p < 32; p++){
      const uint4* pr = (const uint4*)(PATB + p * 1024 + (l << 4));
      float pw[16];
      unpack8(pr[0], pw); unpack8(pr[1], pw + 8);
      float a = 0.f;
#pragma unroll
      for (int i = 0; i < 16; i++) a += w[i] * pw[i];
#pragma unroll
      for (int s = 1; s < 64; s <<= 1) a += __shfl_xor(a, s);
      if (l == 0) PVB[p * 1024 + d] = f2bf(a);
    }
  }
}

// ---------------- main bf16 GEMM (128x128 tile): out[m][n] = A[m].B[n] -------
// 1D grid, XCD swizzle: id = xcd + 8*(n + GN*mq); m-tile = mq*8+xcd.
// MODE 0: bf16(acc) 1: bf16(acc+bias) 2: bf16(acc+bias+Xadd) 3: bf16(gelu) 4: fp32(acc+bias)
template<int MODE, int GN>
__global__ __launch_bounds__(256) void k_gemm_bt(const ushort_t* __restrict__ A,
                                                 const ushort_t* __restrict__ B,
                                                 void* __restrict__ C,
                                                 const float* __restrict__ bias,
                                                 const float* __restrict__ Xadd,
                                                 int N, int K){
  __shared__ ushort_t As[128 * 32];
  __shared__ ushort_t Bs[128 * 32];
  const int tid = threadIdx.x;
  const int w = tid >> 6, l = tid & 63;
  const int id = blockIdx.x;
  const int xcd = id & 7;
  const int t2 = id >> 3;
  const int nt = t2 % GN;
  const int mt = ((t2 / GN) << 3) + xcd;
  const int m0 = mt << 7, n0 = nt << 7;
  const int wm = (w >> 1) << 6, wn = (w & 1) << 6;
  const int rA = (w << 4) + (l >> 2);
  const int cA = (l & 3) << 3;
  const int fr = l & 15, fq = l >> 4;

  floatx4 acc[4][4];
#pragma unroll
  for (int i = 0; i < 4; i++)
#pragma unroll
    for (int j = 0; j < 4; j++) acc[i][j] = (floatx4)0.0f;

  const ushort_t* Ab = A + (size_t)(m0 + rA) * K + cA;
  const ushort_t* Bb = B + (size_t)(n0 + rA) * K + cA;
  const size_t row64 = (size_t)64 * K;
  ushort_t* Asw = As + (w << 9);
  ushort_t* Bsw = Bs + (w << 9);

  for (int k0 = 0; k0 < K; k0 += 32){
    __syncthreads();
    gload16(Ab + k0, Asw);
    gload16(Ab + row64 + k0, Asw + 2048);
    gload16(Bb + k0, Bsw);
    gload16(Bb + row64 + k0, Bsw + 2048);
    __syncthreads();
    short8 af[4], bg[4];
#pragma unroll
    for (int i = 0; i < 4; i++){
      af[i] = *(const short8*)(As + ((wm + (i << 4) + fr) << 5) + (fq << 3));
      bg[i] = *(const short8*)(Bs + ((wn + (i << 4) + fr) << 5) + (fq << 3));
    }
#pragma unroll
    for (int i = 0; i < 4; i++)
#pragma unroll
      for (int j = 0; j < 4; j++)
        acc[i][j] = __builtin_amdgcn_mfma_f32_16x16x32_bf16(af[i], bg[j], acc[i][j], 0, 0, 0);
  }

#pragma unroll
  for (int i = 0; i < 4; i++){
    int row = m0 + wm + (i << 4) + (fq << 2);
#pragma unroll
    for (int j = 0; j < 4; j++){
      int col = n0 + wn + (j << 4) + fr;
      float b = (MODE >= 1) ? bias[col] : 0.0f;
#pragma unroll
      for (int r = 0; r < 4; r++){
        float v = acc[i][j][r] + b;
        size_t idx = (size_t)(row + r) * N + col;
        if (MODE == 2) v += Xadd[idx];
        if (MODE == 3) v = 0.5f * v * (1.0f + erff(v * 0.70710678118654752f));
        if (MODE == 4) ((float*)C)[idx] = v;
        else           ((ushort_t*)C)[idx] = f2bf(v);
      }
    }
  }
}

// ---------------- 64x128-tile GEMM (small-M shapes: 2x the blocks) -----------
template<int MODE, int GN>
__global__ __launch_bounds__(256) void k_gemm_bt64(const ushort_t* __restrict__ A,
                                                   const ushort_t* __restrict__ B,
                                                   void* __restrict__ C,
                                                   const float* __restrict__ bias,
                                                   const float* __restrict__ Xadd,
                                                   int N, int K){
  __shared__ ushort_t As[64 * 32];    // 4 KB
  __shared__ ushort_t Bs[128 * 32];   // 8 KB
  const int tid = threadIdx.x;
  const int w = tid >> 6, l = tid & 63;
  const int id = blockIdx.x;
  const int xcd = id & 7;
  const int t2 = id >> 3;
  const int nt = t2 % GN;
  const int mt = ((t2 / GN) << 3) + xcd;
  const int m0 = mt << 6, n0 = nt << 7;
  const int wm = (w >> 1) << 5, wn = (w & 1) << 6;   // wave: 32x64 of the 64x128 tile
  const int rA = (w << 4) + (l >> 2);
  const int cA = (l & 3) << 3;
  const int fr = l & 15, fq = l >> 4;

  floatx4 acc[2][4];
#pragma unroll
  for (int i = 0; i < 2; i++)
#pragma unroll
    for (int j = 0; j < 4; j++) acc[i][j] = (floatx4)0.0f;

  const ushort_t* Ab = A + (size_t)(m0 + rA) * K + cA;
  const ushort_t* Bb = B + (size_t)(n0 + rA) * K + cA;
  const size_t row64 = (size_t)64 * K;

  for (int k0 = 0; k0 < K; k0 += 32){
    __syncthreads();
    gload16(Ab + k0, As + (w << 9));
    gload16(Bb + k0, Bs + (w << 9));
    gload16(Bb + row64 + k0, Bs + 2048 + (w << 9));
    __syncthreads();
    short8 af[2], bg[4];
#pragma unroll
    for (int i = 0; i < 2; i++)
      af[i] = *(const short8*)(As + ((wm + (i << 4) + fr) << 5) + (fq << 3));
#pragma unroll
    for (int j = 0; j < 4; j++)
      bg[j] = *(const short8*)(Bs + ((wn + (j << 4) + fr) << 5) + (fq << 3));
#pragma unroll
    for (int i = 0; i < 2; i++)
#pragma unroll
      for (int j = 0; j < 4; j++)
        acc[i][j] = __builtin_amdgcn_mfma_f32_16x16x32_bf16(af[i], bg[j], acc[i][j], 0, 0, 0);
  }

#pragma unroll
  for (int i = 0; i < 2; i++){
    int row = m0 + wm + (i << 4) + (fq << 2);
#pragma unroll
    for (int j = 0; j < 4; j++){
      int col = n0 + wn + (j << 4) + fr;
      float b = (MODE >= 1) ? bias[col] : 0.0f;
#pragma unroll
      for (int r = 0; r < 4; r++){
        float v = acc[i][j][r] + b;
        size_t idx = (size_t)(row + r) * N + col;
        if (MODE == 2) v += Xadd[idx];
        if (MODE == 3) v = 0.5f * v * (1.0f + erff(v * 0.70710678118654752f));
        if (MODE == 4) ((float*)C)[idx] = v;
        else           ((ushort_t*)C)[idx] = f2bf(v);
      }
    }
  }
}

// ---------------- skinny N=32 GEMM: C[m][p] = A[m].B[p] ----------------------
__global__ __launch_bounds__(256) void k_gemm_n32(const ushort_t* __restrict__ A,
                                                  const ushort_t* __restrict__ B,
                                                  float* __restrict__ C,
                                                  int K){
  __shared__ ushort_t As[128 * 32];
  __shared__ ushort_t Bs[32 * 32];
  const int tid = threadIdx.x;
  const int w = tid >> 6, l = tid & 63;
  const int m0 = blockIdx.x << 7;
  const int rA = (w << 4) + (l >> 2);
  const int cA = (l & 3) << 3;
  const int fr = l & 15, fq = l >> 4;

  floatx4 acc[2][2];
#pragma unroll
  for (int i = 0; i < 2; i++)
#pragma unroll
    for (int j = 0; j < 2; j++) acc[i][j] = (floatx4)0.0f;

  const ushort_t* Ab = A + (size_t)(m0 + rA) * K + cA;
  const ushort_t* Bb = B + (size_t)rA * K + cA;    // valid rows only for w<2
  const size_t row64 = (size_t)64 * K;

  for (int k0 = 0; k0 < K; k0 += 32){
    __syncthreads();
    gload16(Ab + k0, As + (w << 9));
    gload16(Ab + row64 + k0, As + 2048 + (w << 9));
    if (w < 2) gload16(Bb + k0, Bs + (w << 9));
    __syncthreads();
    short8 af[2], bg[2];
#pragma unroll
    for (int i = 0; i < 2; i++)
      af[i] = *(const short8*)(As + (((w << 5) + (i << 4) + fr) << 5) + (fq << 3));
#pragma unroll
    for (int j = 0; j < 2; j++)
      bg[j] = *(const short8*)(Bs + (((j << 4) + fr) << 5) + (fq << 3));
#pragma unroll
    for (int i = 0; i < 2; i++)
#pragma unroll
      for (int j = 0; j < 2; j++)
        acc[i][j] = __builtin_amdgcn_mfma_f32_16x16x32_bf16(af[i], bg[j], acc[i][j], 0, 0, 0);
  }

#pragma unroll
  for (int i = 0; i < 2; i++){
    int row = m0 + (w << 5) + (i << 4) + (fq << 2);
#pragma unroll
    for (int j = 0; j < 2; j++){
      int col = (j << 4) + fr;
#pragma unroll
      for (int r = 0; r < 4; r++)
        C[(size_t)(row + r) * 32 + col] = acc[i][j][r];
    }
  }
}

// ---------------- fused attention: logits+NPRE (MFMA) -> softmax/top-4 -> gsn -
// block = 4 waves = 4 token-pairs = 8 tokens. Per wave, one K-loop computes
// logits (T x SN) AND NPRE (PV x SN) sharing the SN B-fragment.
__global__ __launch_bounds__(256) void k_attn(const ushort_t* __restrict__ T,
                                              const ushort_t* __restrict__ SNB,
                                              const ushort_t* __restrict__ PVB,
                                              const float* __restrict__ PBv,
                                              const float* __restrict__ CB,
                                              const float* __restrict__ TW,
                                              ushort_t* __restrict__ GSN){
  __shared__ float logit_s[4 * 256];
  __shared__ float attn_s[8 * 64];
  __shared__ float npr_s[8 * 256];
  __shared__ float nps_s[8 * 256];
  __shared__ float sc_s[8 * 32];
  __shared__ float tw_s[8 * 8];
  __shared__ float pb_s[32];
  __shared__ int   sel_s[8 * 4];
  __shared__ float tkw_s[8 * 4], rmax_s[8 * 4], rsum_s[8 * 4], fa_s[8 * 8], g_s[8 * 8];

  const int t = threadIdx.x;
  const int w = t >> 6, l = t & 63;
  const int tok0 = blockIdx.x << 3;
  const int pair = (blockIdx.x << 2) + w;

  { // MFMA: logits + NPRE for this wave's pair, fragments straight from global
    const size_t rbase = (size_t)pair * 16 + (l & 15);
    const int ko = (l >> 4) << 3;
    const ushort_t* Ap = T   + rbase * 1024 + ko;
    const ushort_t* Bp = SNB + rbase * 1024 + ko;
    const ushort_t* P0 = PVB + (size_t)(l & 15) * 1024 + ko;          // patterns 0-15
    const ushort_t* P1 = P0 + 16 * 1024;                              // patterns 16-31
    floatx4 aL = (floatx4)0.0f, aP0 = (floatx4)0.0f, aP1 = (floatx4)0.0f;
#pragma unroll 4
    for (int k0 = 0; k0 < 1024; k0 += 32){
      short8 b = *(const short8*)(Bp + k0);
      aL  = __builtin_amdgcn_mfma_f32_16x16x32_bf16(*(const short8*)(Ap + k0), b, aL, 0, 0, 0);
      aP0 = __builtin_amdgcn_mfma_f32_16x16x32_bf16(*(const short8*)(P0 + k0), b, aP0, 0, 0, 0);
      aP1 = __builtin_amdgcn_mfma_f32_16x16x32_bf16(*(const short8*)(P1 + k0), b, aP1, 0, 0, 0);
    }
    const int col = l & 15, r0 = (l >> 4) << 2;
#pragma unroll
    for (int r = 0; r < 4; r++)
      logit_s[(w << 8) + (r0 + r) * 16 + col] = aL[r] * 0.03125f;
    // NPRE: D[i][j] = PV_i . SN_j ; j -> (token j>>3, k=j&7), i -> pattern
    const int tokloc = (w << 1) + (col >> 3), kk = col & 7;
#pragma unroll
    for (int r = 0; r < 4; r++){
      npr_s[(tokloc << 8) + kk * 32 + (r0 + r)]      = aP0[r];
      npr_s[(tokloc << 8) + kk * 32 + (r0 + r) + 16] = aP1[r];
    }
  }
  if (t < 64) tw_s[t] = TW[(tok0 << 3) + t];
  if (t < 32) pb_s[t] = PBv[t];
  __syncthreads();

  const int loc = t >> 5, q = t & 31;    // token-in-block, lane-in-token-group
  if (q < 8){ // softmax of logit row q for token loc
    const float* lrow = logit_s + ((loc >> 1) << 8) + (loc & 1) * 136 + q * 16;
    float a[8]; float m = -1e30f;
#pragma unroll
    for (int j = 0; j < 8; j++){ a[j] = lrow[j]; m = fmaxf(m, a[j]); }
    float s = 0.f;
#pragma unroll
    for (int j = 0; j < 8; j++){ a[j] = expf(a[j] - m); s += a[j]; }
    float inv = 1.f / s;
#pragma unroll
    for (int j = 0; j < 8; j++) attn_s[(loc << 6) + q * 8 + j] = a[j] * inv;
  }
  __syncthreads();

  { // nps: column qq = q&7, patterns (q>>3)*8..+7 ; +pb (rows of attn sum to 1)
    const int qq = q & 7, p0 = (q >> 3) << 3;
    float a[8];
#pragma unroll
    for (int k = 0; k < 8; k++) a[k] = attn_s[(loc << 6) + qq * 8 + k];
    const float* np = npr_s + (loc << 8);
    float* npsr = nps_s + (loc << 8);
    for (int p = p0; p < p0 + 8; p++){
      float acc = pb_s[p];
#pragma unroll
      for (int k = 0; k < 8; k++) acc += a[k] * np[k * 32 + p];
      npsr[p * 8 + qq] = acc * 0.03125f;
    }
  }
  __syncthreads();

  { // scores, p = q
    const float* npsr = nps_s + (loc << 8);
    float nb = 0.f;
#pragma unroll
    for (int qq = 0; qq < 8; qq++) nb += npsr[q * 8 + qq] * tw_s[(loc << 3) + qq];
    sc_s[(loc << 5) + q] = 0.5f * nb + 0.5f * CB[((size_t)(tok0 + loc) << 5) + q];
  }
  __syncthreads();

  if (q == 0){ // top-4 (stable: first index wins ties, like lax.top_k)
    const float* sc = sc_s + (loc << 5);
    unsigned used = 0; float vals[4]; int idx[4];
    for (int kp = 0; kp < 4; kp++){
      float best = -1e30f; int bi = 0;
      for (int p = 0; p < 32; p++)
        if (!((used >> p) & 1u) && sc[p] > best){ best = sc[p]; bi = p; }
      used |= 1u << bi; vals[kp] = best; idx[kp] = bi;
    }
    float mm = vals[0], ss = 0.f, e[4];
    for (int kp = 0; kp < 4; kp++){ e[kp] = expf(vals[kp] - mm); ss += e[kp]; }
    for (int kp = 0; kp < 4; kp++){ tkw_s[(loc << 2) + kp] = e[kp] / ss; sel_s[(loc << 2) + kp] = idx[kp]; }
  }
  __syncthreads();

  if (q < 4){ // row softmax stats for selected patterns
    const float* npsr = nps_s + (loc << 8);
    int p = sel_s[(loc << 2) + q];
    float mm = -1e30f;
    for (int j = 0; j < 8; j++) mm = fmaxf(mm, npsr[p * 8 + j]);
    float ss = 0.f;
    for (int j = 0; j < 8; j++) ss += expf(npsr[p * 8 + j] - mm);
    rmax_s[(loc << 2) + q] = mm; rsum_s[(loc << 2) + q] = ss;
  }
  __syncthreads();

  if (q < 8){ // final_attn
    const float* npsr = nps_s + (loc << 8);
    float f = 0.f;
    for (int kp = 0; kp < 4; kp++){
      int p = sel_s[(loc << 2) + kp];
      f += tkw_s[(loc << 2) + kp] * expf(npsr[p * 8 + q] - rmax_s[(loc << 2) + kp]) / rsum_s[(loc << 2) + kp];
    }
    fa_s[(loc << 3) + q] = f;
  }
  __syncthreads();

  if (q < 8){ // g = fa @ attn
    float g = 0.f;
    for (int qq = 0; qq < 8; qq++) g += fa_s[(loc << 3) + qq] * attn_s[(loc << 6) + qq * 8 + q];
    g_s[(loc << 3) + q] = g;
  }
  __syncthreads();

  // gsn: each wave handles its pair's 2 tokens; SNB rows are L1/L2-hot
  for (int tl = 0; tl < 2; tl++){
    const int tkl = (w << 1) + tl;
    const size_t tok = (size_t)tok0 + tkl;
    float o[16];
#pragma unroll
    for (int i = 0; i < 16; i++) o[i] = 0.f;
#pragma unroll
    for (int k = 0; k < 8; k++){
      float gk = g_s[(tkl << 3) + k];
      const uint4* src = (const uint4*)(SNB + ((tok << 3) + k) * 1024 + (l << 4));
      float f0[8], f1[8];
      unpack8(src[0], f0);
      unpack8(src[1], f1);
#pragma unroll
      for (int i = 0; i < 8; i++){ o[i] += gk * f0[i]; o[8 + i] += gk * f1[i]; }
    }
    uint4* dst = (uint4*)(GSN + tok * 1024 + (l << 4));
    dst[0] = pack8(o);
    dst[1] = pack8(o + 8);
  }
}

extern "C" void kernel_launch(void* const* d_in, const int* in_sizes, int n_in,
                              void* d_out, int out_size, void* d_ws, size_t ws_size,
                              hipStream_t stream){
  (void)in_sizes; (void)n_in; (void)out_size; (void)ws_size;
  const float* x   = (const float*)d_in[0];
  const float* tw  = (const float*)d_in[3];
  const float* SN  = (const float*)d_in[4];
  const float* ctx = (const float*)d_in[5];
  const float* Wq  = (const float*)d_in[6];
  const float* bq  = (const float*)d_in[7];
  const float* Wk  = (const float*)d_in[8];
  const float* Wv  = (const float*)d_in[10];
  const float* bv  = (const float*)d_in[11];
  const float* pat = (const float*)d_in[12];
  const float* Wup = (const float*)d_in[13];
  const float* bup = (const float*)d_in[14];
  const float* Wdn = (const float*)d_in[15];
  const float* bdn = (const float*)d_in[16];
  float* out = (float*)d_out;

  char* ws = (char*)d_ws;
  size_t off = 0;
  auto alloc = [&](size_t bytes) -> char* {
    char* p = ws + off;
    off = (off + bytes + 255) & ~(size_t)255;
    return p;
  };
  ushort_t* SNB  = (ushort_t*)alloc(67108864);  // SN bf16 [32768][1024]; later aliased by H
  ushort_t* TB   = (ushort_t*)alloc(67108864);  // T bf16; later aliased by COMBINED
  float*    CBb  = (float*)alloc(524288);       // [4096][32]
  ushort_t* GSN  = (ushort_t*)alloc(8388608);   // [4096][1024] bf16
  ushort_t* CTXB = (ushort_t*)alloc(8388608);
  ushort_t* PATB = (ushort_t*)alloc(65536);
  ushort_t* WVB  = (ushort_t*)alloc(2097152);
  ushort_t* WUPB = (ushort_t*)alloc(8388608);
  ushort_t* WDNB = (ushort_t*)alloc(8388608);
  ushort_t* ATB  = (ushort_t*)alloc(2097152);
  ushort_t* WKTB = (ushort_t*)alloc(2097152);
  ushort_t* WQTB = (ushort_t*)alloc(2097152);
  ushort_t* WVTB = (ushort_t*)alloc(2097152);
  ushort_t* PVB  = (ushort_t*)alloc(65536);
  float*    WVEC = (float*)alloc(4096);
  float*    PBv  = (float*)alloc(128);
  ushort_t* H    = SNB;   // 32MB alias (SNB dead by FFN time)
  ushort_t* CMB  = TB;    // 8MB alias (T dead after k_attn)

  // converts (one launch) + transposes (one launch) + prep (one launch)
  const int e0 = 8388608, e1 = e0 + 1048576, e2 = e1 + 8192,
            e3 = e2 + 262144, e4 = e3 + 1048576, e5 = e4 + 1048576;
  k_cvt_multi<<<(e5 + 255) / 256, 256, 0, stream>>>(
      SN, SNB, e0, ctx, CTXB, e1, pat, PATB, e2,
      Wv, WVB, e3, Wup, WUPB, e4, Wdn, WDNB, e5);
  k_transpose3<<<dim3(32, 32, 3), 256, 0, stream>>>(Wq, WQTB, Wk, WKTB, Wv, WVTB);
  k_prep<<<520, 256, 0, stream>>>(bq, WKTB, WVEC, pat, bv, PBv, WVTB, PATB, PVB);

  // At[d'][d] = sum_e Wk[e][d']*Wq[e][d]   (64x128 tiles, 128 blocks)
  k_gemm_bt64<0, 8><<<128, 256, 0, stream>>>(WKTB, WQTB, ATB, nullptr, nullptr, 1024, 1024);
  // T = SN @ At^T + wvec  (wvec folds the bq bias; row-constant terms cancel in softmax)
  k_gemm_bt<1, 8><<<2048, 256, 0, stream>>>(SNB, ATB, TB, WVEC, nullptr, 1024, 1024);
  // CB[tok][p] = context[tok] . pattern[p]
  k_gemm_n32<<<32, 256, 0, stream>>>(CTXB, PATB, CBb, 1024);
  // fused: logits+NPRE (MFMA) -> softmax/top-4/final_attn -> gsn
  k_attn<<<512, 256, 0, stream>>>(TB, SNB, PVB, PBv, CBb, tw, GSN);
  // combined = gsn @ Wv^T + bv + x   (bf16, 64x128 tiles, 512 blocks)
  k_gemm_bt64<2, 8><<<512, 256, 0, stream>>>(GSN, WVB, CMB, bv, x, 1024, 1024);
  // H = gelu(combined @ Wup^T + bup) (bf16)
  k_gemm_bt<3, 32><<<1024, 256, 0, stream>>>(CMB, WUPB, H, bup, nullptr, 4096, 1024);
  // out = H @ Wdown^T + bdown        (fp32, 64x128 tiles, 512 blocks)
  k_gemm_bt64<4, 8><<<512, 256, 0, stream>>>(H, WDNB, out, bdn, nullptr, 1024, 4096);
}

// Round 5
// 630.294 us; speedup vs baseline: 1.4057x; 1.0004x over previous
//
#include <hip/hip_runtime.h>
#include <math.h>

// B=2,S=2048 -> NT=4096 tokens; K=8, D=1024, P=32, KP=4, DFF=4096
typedef unsigned short ushort_t;
typedef __attribute__((ext_vector_type(8))) short short8;
typedef __attribute__((ext_vector_type(4))) float floatx4;

static __device__ __forceinline__ ushort_t f2bf(float f){
  unsigned int u = __float_as_uint(f);
  unsigned int r = u + 0x7FFFu + ((u >> 16) & 1u);   // round-to-nearest-even
  return (ushort_t)(r >> 16);
}
static __device__ __forceinline__ void unpack8(uint4 u, float* f){
  f[0] = __uint_as_float(u.x << 16); f[1] = __uint_as_float(u.x & 0xffff0000u);
  f[2] = __uint_as_float(u.y << 16); f[3] = __uint_as_float(u.y & 0xffff0000u);
  f[4] = __uint_as_float(u.z << 16); f[5] = __uint_as_float(u.z & 0xffff0000u);
  f[6] = __uint_as_float(u.w << 16); f[7] = __uint_as_float(u.w & 0xffff0000u);
}
static __device__ __forceinline__ uint4 pack8(const float* f){
  uint4 u;
  u.x = (unsigned)f2bf(f[0]) | ((unsigned)f2bf(f[1]) << 16);
  u.y = (unsigned)f2bf(f[2]) | ((unsigned)f2bf(f[3]) << 16);
  u.z = (unsigned)f2bf(f[4]) | ((unsigned)f2bf(f[5]) << 16);
  u.w = (unsigned)f2bf(f[6]) | ((unsigned)f2bf(f[7]) << 16);
  return u;
}

static __device__ __forceinline__ void gload16(const void* g, void* l){
  __builtin_amdgcn_global_load_lds((const __attribute__((address_space(1))) void*)g,
                                   (__attribute__((address_space(3))) void*)l, 16, 0, 0);
}

// gelu(x) ~= x * sigmoid(1.5957691216 x + 0.0713548162 x^3)  (tanh form, hw exp)
static __device__ __forceinline__ float gelu_f(float v){
  float w = v * (-1.5957691216f - 0.0713548162f * v * v);
  return v / (1.0f + __expf(w));
}

// ------ merged fp32 -> bf16 converts (6 tensors) + out=bdn broadcast init ----
__global__ __launch_bounds__(256) void k_cvt_multi(
    const float* __restrict__ s0, ushort_t* __restrict__ d0, int e0,
    const float* __restrict__ s1, ushort_t* __restrict__ d1, int e1,
    const float* __restrict__ s2, ushort_t* __restrict__ d2, int e2,
    const float* __restrict__ s3, ushort_t* __restrict__ d3, int e3,
    const float* __restrict__ s4, ushort_t* __restrict__ d4, int e4,
    const float* __restrict__ s5, ushort_t* __restrict__ d5, int e5,
    const float* __restrict__ bdn, float* __restrict__ outp, int e6){
  int i = blockIdx.x * 256 + threadIdx.x;
  if (i >= e5){                       // stream 7: fill out rows with bdn
    if (i < e6){
      int j = i - e5;
      ((float4*)outp)[j] = ((const float4*)bdn)[j & 255];
    }
    return;
  }
  const float* s; ushort_t* d; int b;
  if      (i < e0){ s = s0; d = d0; b = 0;  }
  else if (i < e1){ s = s1; d = d1; b = e0; }
  else if (i < e2){ s = s2; d = d2; b = e1; }
  else if (i < e3){ s = s3; d = d3; b = e2; }
  else if (i < e4){ s = s4; d = d4; b = e3; }
  else            { s = s5; d = d5; b = e4; }
  int j = i - b;
  float4 v = ((const float4*)s)[j];
  unsigned long long p = (unsigned long long)f2bf(v.x)
                       | ((unsigned long long)f2bf(v.y) << 16)
                       | ((unsigned long long)f2bf(v.z) << 32)
                       | ((unsigned long long)f2bf(v.w) << 48);
  ((unsigned long long*)d)[j] = p;
}

// ---------------- 3x 1024x1024 transpose with bf16 convert (one launch) -------
__global__ __launch_bounds__(256) void k_transpose3(const float* __restrict__ s0, ushort_t* __restrict__ d0,
                                                    const float* __restrict__ s1, ushort_t* __restrict__ d1,
                                                    const float* __restrict__ s2, ushort_t* __restrict__ d2){
  __shared__ float tile[32][33];
  const float* in; ushort_t* out;
  if      (blockIdx.z == 0){ in = s0; out = d0; }
  else if (blockIdx.z == 1){ in = s1; out = d1; }
  else                     { in = s2; out = d2; }
  int bx = blockIdx.x * 32, by = blockIdx.y * 32;
  int tx = threadIdx.x & 31, ty = threadIdx.x >> 5;   // ty 0..7
  for (int i = 0; i < 32; i += 8)
    tile[ty + i][tx] = in[(size_t)(by + ty + i) * 1024 + bx + tx];
  __syncthreads();
  for (int i = 0; i < 32; i += 8)
    out[(size_t)(bx + ty + i) * 1024 + by + tx] = f2bf(tile[tx][ty + i]);
}

// ---------------- merged prep: wvec (256 blk) | pb (8 blk) | PV (256 blk) -----
__global__ __launch_bounds__(256) void k_prep(const float* __restrict__ bq,
                                              const ushort_t* __restrict__ WKT,
                                              float* __restrict__ wv,
                                              const float* __restrict__ pat,
                                              const float* __restrict__ bv,
                                              float* __restrict__ pb,
                                              const ushort_t* __restrict__ WVT,
                                              const ushort_t* __restrict__ PATB,
                                              ushort_t* __restrict__ PVB){
  const int bid = blockIdx.x;
  const int l = threadIdx.x & 63;
  if (bid < 256){            // wvec
    int d = (bid << 2) + (threadIdx.x >> 6);
    const uint4* row = (const uint4*)(WKT + (size_t)d * 1024 + (l << 4));
    const float4* b4 = (const float4*)(bq + (l << 4));
    float w[16], bb[16];
    unpack8(row[0], w); unpack8(row[1], w + 8);
#pragma unroll
    for (int i = 0; i < 4; i++){
      float4 v = b4[i];
      bb[i*4] = v.x; bb[i*4+1] = v.y; bb[i*4+2] = v.z; bb[i*4+3] = v.w;
    }
    float a = 0.f;
#pragma unroll
    for (int i = 0; i < 16; i++) a += w[i] * bb[i];
#pragma unroll
    for (int s = 1; s < 64; s <<= 1) a += __shfl_xor(a, s);
    if (l == 0) wv[d] = a;
  } else if (bid < 264){     // pb
    int p = ((bid - 256) << 2) + (threadIdx.x >> 6);
    const float4* pr = (const float4*)(pat + p * 1024) + l;
    const float4* b4 = (const float4*)bv + l;
    float a = 0.f;
#pragma unroll
    for (int i = 0; i < 4; i++){
      float4 x = pr[i * 64], y = b4[i * 64];
      a += x.x * y.x + x.y * y.y + x.z * y.z + x.w * y.w;
    }
#pragma unroll
    for (int s = 1; s < 64; s <<= 1) a += __shfl_xor(a, s);
    if (l == 0) pb[p] = a;
  } else {                   // PV
    int d = ((bid - 264) << 2) + (threadIdx.x >> 6);
    const uint4* wr = (const uint4*)(WVT + (size_t)d * 1024 + (l << 4));
    float w[16];
    unpack8(wr[0], w); unpack8(wr[1], w + 8);
    for (int p = 0; p < 32; p++){
      const uint4* pr = (const uint4*)(PATB + p * 1024 + (l << 4));
      float pw[16];
      unpack8(pr[0], pw); unpack8(pr[1], pw + 8);
      float a = 0.f;
#pragma unroll
      for (int i = 0; i < 16; i++) a += w[i] * pw[i];
#pragma unroll
      for (int s = 1; s < 64; s <<= 1) a += __shfl_xor(a, s);
      if (l == 0) PVB[p * 1024 + d] = f2bf(a);
    }
  }
}

// ---------------- main bf16 GEMM (128x128 tile): out[m][n] = A[m].B[n] -------
// 1D grid, XCD swizzle + n-group-of-NG for L2 reuse of B:
//   xcd = id&7; per-XCD blocks enumerated as (g, mq, nw): nt = g*NG+nw.
//   Working set per phase: NG B-tiles + cycling A-tiles -> fits 4MB XCD L2.
// MODE 0: bf16(acc) 1: bf16(acc+bias) 2: bf16(acc+bias+Xadd) 3: bf16(gelu) 4: fp32(acc+bias)
template<int MODE, int GN, int NG>
__global__ __launch_bounds__(256) void k_gemm_bt(const ushort_t* __restrict__ A,
                                                 const ushort_t* __restrict__ B,
                                                 void* __restrict__ C,
                                                 const float* __restrict__ bias,
                                                 const float* __restrict__ Xadd,
                                                 int N, int K){
  __shared__ ushort_t As[128 * 32];
  __shared__ ushort_t Bs[128 * 32];
  const int tid = threadIdx.x;
  const int w = tid >> 6, l = tid & 63;
  const int id = blockIdx.x;
  const int xcd = id & 7;
  const int t2 = id >> 3;
  const int nmq = (int)(gridDim.x >> 3) / GN;   // m-tile count per XCD
  const int gsz = nmq * NG;
  const int g = t2 / gsz, r = t2 - g * gsz;
  const int mq = r / NG, nw = r - mq * NG;
  const int nt = g * NG + nw;
  const int mt = (mq << 3) + xcd;
  const int m0 = mt << 7, n0 = nt << 7;
  const int wm = (w >> 1) << 6, wn = (w & 1) << 6;
  const int rA = (w << 4) + (l >> 2);
  const int cA = (l & 3) << 3;
  const int fr = l & 15, fq = l >> 4;

  floatx4 acc[4][4];
#pragma unroll
  for (int i = 0; i < 4; i++)
#pragma unroll
    for (int j = 0; j < 4; j++) acc[i][j] = (floatx4)0.0f;

  const ushort_t* Ab = A + (size_t)(m0 + rA) * K + cA;
  const ushort_t* Bb = B + (size_t)(n0 + rA) * K + cA;
  const size_t row64 = (size_t)64 * K;
  ushort_t* Asw = As + (w << 9);
  ushort_t* Bsw = Bs + (w << 9);

  for (int k0 = 0; k0 < K; k0 += 32){
    __syncthreads();
    gload16(Ab + k0, Asw);
    gload16(Ab + row64 + k0, Asw + 2048);
    gload16(Bb + k0, Bsw);
    gload16(Bb + row64 + k0, Bsw + 2048);
    __syncthreads();
    short8 af[4], bg[4];
#pragma unroll
    for (int i = 0; i < 4; i++){
      af[i] = *(const short8*)(As + ((wm + (i << 4) + fr) << 5) + (fq << 3));
      bg[i] = *(const short8*)(Bs + ((wn + (i << 4) + fr) << 5) + (fq << 3));
    }
#pragma unroll
    for (int i = 0; i < 4; i++)
#pragma unroll
      for (int j = 0; j < 4; j++)
        acc[i][j] = __builtin_amdgcn_mfma_f32_16x16x32_bf16(af[i], bg[j], acc[i][j], 0, 0, 0);
  }

#pragma unroll
  for (int i = 0; i < 4; i++){
    int row = m0 + wm + (i << 4) + (fq << 2);
#pragma unroll
    for (int j = 0; j < 4; j++){
      int col = n0 + wn + (j << 4) + fr;
      float b = (MODE >= 1) ? bias[col] : 0.0f;
#pragma unroll
      for (int r2 = 0; r2 < 4; r2++){
        float v = acc[i][j][r2] + b;
        size_t idx = (size_t)(row + r2) * N + col;
        if (MODE == 2) v += Xadd[idx];
        if (MODE == 3) v = gelu_f(v);
        if (MODE == 4) ((float*)C)[idx] = v;
        else           ((ushort_t*)C)[idx] = f2bf(v);
      }
    }
  }
}

// ------- 64x128-tile GEMM, optional split-K (KS) with fp32 atomic output -----
// Per XCD enumeration: (nt, mq, kh) with kh fastest -> B-tile L2-resident,
// both kh-halves of a tile adjacent on the same XCD.
// MODE 0: bf16(acc) 2: bf16(acc+bias+Xadd) 5: atomicAdd fp32 (bias pre-filled)
template<int MODE, int GN, int KS>
__global__ __launch_bounds__(256) void k_gemm_bt64(const ushort_t* __restrict__ A,
                                                   const ushort_t* __restrict__ B,
                                                   void* __restrict__ C,
                                                   const float* __restrict__ bias,
                                                   const float* __restrict__ Xadd,
                                                   int N, int K){
  __shared__ ushort_t As[64 * 32];    // 4 KB
  __shared__ ushort_t Bs[128 * 32];   // 8 KB
  const int tid = threadIdx.x;
  const int w = tid >> 6, l = tid & 63;
  const int id = blockIdx.x;
  const int xcd = id & 7;
  const int t2 = id >> 3;
  const int nmq = (int)(gridDim.x >> 3) / (GN * KS);
  const int nt = t2 / (nmq * KS);
  const int r2 = t2 - nt * (nmq * KS);
  const int mq = r2 / KS, kh = r2 - mq * KS;
  const int mt = (mq << 3) + xcd;
  const int m0 = mt << 6, n0 = nt << 7;
  const int kbase = kh * (K / KS);
  const int wm = (w >> 1) << 5, wn = (w & 1) << 6;   // wave: 32x64 of the 64x128 tile
  const int rA = (w << 4) + (l >> 2);
  const int cA = (l & 3) << 3;
  const int fr = l & 15, fq = l >> 4;

  floatx4 acc[2][4];
#pragma unroll
  for (int i = 0; i < 2; i++)
#pragma unroll
    for (int j = 0; j < 4; j++) acc[i][j] = (floatx4)0.0f;

  const ushort_t* Ab = A + (size_t)(m0 + rA) * K + cA + kbase;
  const ushort_t* Bb = B + (size_t)(n0 + rA) * K + cA + kbase;
  const size_t row64 = (size_t)64 * K;
  const int klen = K / KS;

  for (int k0 = 0; k0 < klen; k0 += 32){
    __syncthreads();
    gload16(Ab + k0, As + (w << 9));
    gload16(Bb + k0, Bs + (w << 9));
    gload16(Bb + row64 + k0, Bs + 2048 + (w << 9));
    __syncthreads();
    short8 af[2], bg[4];
#pragma unroll
    for (int i = 0; i < 2; i++)
      af[i] = *(const short8*)(As + ((wm + (i << 4) + fr) << 5) + (fq << 3));
#pragma unroll
    for (int j = 0; j < 4; j++)
      bg[j] = *(const short8*)(Bs + ((wn + (j << 4) + fr) << 5) + (fq << 3));
#pragma unroll
    for (int i = 0; i < 2; i++)
#pragma unroll
      for (int j = 0; j < 4; j++)
        acc[i][j] = __builtin_amdgcn_mfma_f32_16x16x32_bf16(af[i], bg[j], acc[i][j], 0, 0, 0);
  }

#pragma unroll
  for (int i = 0; i < 2; i++){
    int row = m0 + wm + (i << 4) + (fq << 2);
#pragma unroll
    for (int j = 0; j < 4; j++){
      int col = n0 + wn + (j << 4) + fr;
      float b = (MODE == 2) ? bias[col] : 0.0f;
#pragma unroll
      for (int r = 0; r < 4; r++){
        float v = acc[i][j][r] + b;
        size_t idx = (size_t)(row + r) * N + col;
        if (MODE == 2) v += Xadd[idx];
        if (MODE == 5) atomicAdd(((float*)C) + idx, v);
        else           ((ushort_t*)C)[idx] = f2bf(v);
      }
    }
  }
}

// ---------------- skinny N=32 GEMM: C[m][p] = A[m].B[p] ----------------------
__global__ __launch_bounds__(256) void k_gemm_n32(const ushort_t* __restrict__ A,
                                                  const ushort_t* __restrict__ B,
                                                  float* __restrict__ C,
                                                  int K){
  __shared__ ushort_t As[128 * 32];
  __shared__ ushort_t Bs[32 * 32];
  const int tid = threadIdx.x;
  const int w = tid >> 6, l = tid & 63;
  const int m0 = blockIdx.x << 7;
  const int rA = (w << 4) + (l >> 2);
  const int cA = (l & 3) << 3;
  const int fr = l & 15, fq = l >> 4;

  floatx4 acc[2][2];
#pragma unroll
  for (int i = 0; i < 2; i++)
#pragma unroll
    for (int j = 0; j < 2; j++) acc[i][j] = (floatx4)0.0f;

  const ushort_t* Ab = A + (size_t)(m0 + rA) * K + cA;
  const ushort_t* Bb = B + (size_t)rA * K + cA;    // valid rows only for w<2
  const size_t row64 = (size_t)64 * K;

  for (int k0 = 0; k0 < K; k0 += 32){
    __syncthreads();
    gload16(Ab + k0, As + (w << 9));
    gload16(Ab + row64 + k0, As + 2048 + (w << 9));
    if (w < 2) gload16(Bb + k0, Bs + (w << 9));
    __syncthreads();
    short8 af[2], bg[2];
#pragma unroll
    for (int i = 0; i < 2; i++)
      af[i] = *(const short8*)(As + (((w << 5) + (i << 4) + fr) << 5) + (fq << 3));
#pragma unroll
    for (int j = 0; j < 2; j++)
      bg[j] = *(const short8*)(Bs + (((j << 4) + fr) << 5) + (fq << 3));
#pragma unroll
    for (int i = 0; i < 2; i++)
#pragma unroll
      for (int j = 0; j < 2; j++)
        acc[i][j] = __builtin_amdgcn_mfma_f32_16x16x32_bf16(af[i], bg[j], acc[i][j], 0, 0, 0);
  }

#pragma unroll
  for (int i = 0; i < 2; i++){
    int row = m0 + (w << 5) + (i << 4) + (fq << 2);
#pragma unroll
    for (int j = 0; j < 2; j++){
      int col = (j << 4) + fr;
#pragma unroll
      for (int r = 0; r < 4; r++)
        C[(size_t)(row + r) * 32 + col] = acc[i][j][r];
    }
  }
}

// ---------------- fused attention: logits+NPRE (MFMA) -> softmax/top-4 -> gsn -
__global__ __launch_bounds__(256) void k_attn(const ushort_t* __restrict__ T,
                                              const ushort_t* __restrict__ SNB,
                                              const ushort_t* __restrict__ PVB,
                                              const float* __restrict__ PBv,
                                              const float* __restrict__ CB,
                                              const float* __restrict__ TW,
                                              ushort_t* __restrict__ GSN){
  __shared__ float logit_s[4 * 256];
  __shared__ float attn_s[8 * 64];
  __shared__ float npr_s[8 * 256];
  __shared__ float nps_s[8 * 256];
  __shared__ float sc_s[8 * 32];
  __shared__ float tw_s[8 * 8];
  __shared__ float pb_s[32];
  __shared__ int   sel_s[8 * 4];
  __shared__ float tkw_s[8 * 4], rmax_s[8 * 4], rsum_s[8 * 4], fa_s[8 * 8], g_s[8 * 8];

  const int t = threadIdx.x;
  const int w = t >> 6, l = t & 63;
  const int tok0 = blockIdx.x << 3;
  const int pair = (blockIdx.x << 2) + w;

  { // MFMA: logits + NPRE for this wave's pair, fragments straight from global
    const size_t rbase = (size_t)pair * 16 + (l & 15);
    const int ko = (l >> 4) << 3;
    const ushort_t* Ap = T   + rbase * 1024 + ko;
    const ushort_t* Bp = SNB + rbase * 1024 + ko;
    const ushort_t* P0 = PVB + (size_t)(l & 15) * 1024 + ko;          // patterns 0-15
    const ushort_t* P1 = P0 + 16 * 1024;                              // patterns 16-31
    floatx4 aL = (floatx4)0.0f, aP0 = (floatx4)0.0f, aP1 = (floatx4)0.0f;
#pragma unroll 4
    for (int k0 = 0; k0 < 1024; k0 += 32){
      short8 b = *(const short8*)(Bp + k0);
      aL  = __builtin_amdgcn_mfma_f32_16x16x32_bf16(*(const short8*)(Ap + k0), b, aL, 0, 0, 0);
      aP0 = __builtin_amdgcn_mfma_f32_16x16x32_bf16(*(const short8*)(P0 + k0), b, aP0, 0, 0, 0);
      aP1 = __builtin_amdgcn_mfma_f32_16x16x32_bf16(*(const short8*)(P1 + k0), b, aP1, 0, 0, 0);
    }
    const int col = l & 15, r0 = (l >> 4) << 2;
#pragma unroll
    for (int r = 0; r < 4; r++)
      logit_s[(w << 8) + (r0 + r) * 16 + col] = aL[r] * 0.03125f;
    // NPRE: D[i][j] = PV_i . SN_j ; j -> (token j>>3, k=j&7), i -> pattern
    const int tokloc = (w << 1) + (col >> 3), kk = col & 7;
#pragma unroll
    for (int r = 0; r < 4; r++){
      npr_s[(tokloc << 8) + kk * 32 + (r0 + r)]      = aP0[r];
      npr_s[(tokloc << 8) + kk * 32 + (r0 + r) + 16] = aP1[r];
    }
  }
  if (t < 64) tw_s[t] = TW[(tok0 << 3) + t];
  if (t < 32) pb_s[t] = PBv[t];
  __syncthreads();

  const int loc = t >> 5, q = t & 31;    // token-in-block, lane-in-token-group
  if (q < 8){ // softmax of logit row q for token loc
    const float* lrow = logit_s + ((loc >> 1) << 8) + (loc & 1) * 136 + q * 16;
    float a[8]; float m = -1e30f;
#pragma unroll
    for (int j = 0; j < 8; j++){ a[j] = lrow[j]; m = fmaxf(m, a[j]); }
    float s = 0.f;
#pragma unroll
    for (int j = 0; j < 8; j++){ a[j] = expf(a[j] - m); s += a[j]; }
    float inv = 1.f / s;
#pragma unroll
    for (int j = 0; j < 8; j++) attn_s[(loc << 6) + q * 8 + j] = a[j] * inv;
  }
  __syncthreads();

  { // nps: column qq = q&7, patterns (q>>3)*8..+7 ; +pb (rows of attn sum to 1)
    const int qq = q & 7, p0 = (q >> 3) << 3;
    float a[8];
#pragma unroll
    for (int k = 0; k < 8; k++) a[k] = attn_s[(loc << 6) + qq * 8 + k];
    const float* np = npr_s + (loc << 8);
    float* npsr = nps_s + (loc << 8);
    for (int p = p0; p < p0 + 8; p++){
      float acc = pb_s[p];
#pragma unroll
      for (int k = 0; k < 8; k++) acc += a[k] * np[k * 32 + p];
      npsr[p * 8 + qq] = acc * 0.03125f;
    }
  }
  __syncthreads();

  { // scores, p = q
    const float* npsr = nps_s + (loc << 8);
    float nb = 0.f;
#pragma unroll
    for (int qq = 0; qq < 8; qq++) nb += npsr[q * 8 + qq] * tw_s[(loc << 3) + qq];
    sc_s[(loc << 5) + q] = 0.5f * nb + 0.5f * CB[((size_t)(tok0 + loc) << 5) + q];
  }
  __syncthreads();

  if (q == 0){ // top-4 (stable: first index wins ties, like lax.top_k)
    const float* sc = sc_s + (loc << 5);
    unsigned used = 0; float vals[4]; int idx[4];
    for (int kp = 0; kp < 4; kp++){
      float best = -1e30f; int bi = 0;
      for (int p = 0; p < 32; p++)
        if (!((used >> p) & 1u) && sc[p] > best){ best = sc[p]; bi = p; }
      used |= 1u << bi; vals[kp] = best; idx[kp] = bi;
    }
    float mm = vals[0], ss = 0.f, e[4];
    for (int kp = 0; kp < 4; kp++){ e[kp] = expf(vals[kp] - mm); ss += e[kp]; }
    for (int kp = 0; kp < 4; kp++){ tkw_s[(loc << 2) + kp] = e[kp] / ss; sel_s[(loc << 2) + kp] = idx[kp]; }
  }
  __syncthreads();

  if (q < 4){ // row softmax stats for selected patterns
    const float* npsr = nps_s + (loc << 8);
    int p = sel_s[(loc << 2) + q];
    float mm = -1e30f;
    for (int j = 0; j < 8; j++) mm = fmaxf(mm, npsr[p * 8 + j]);
    float ss = 0.f;
    for (int j = 0; j < 8; j++) ss += expf(npsr[p * 8 + j] - mm);
    rmax_s[(loc << 2) + q] = mm; rsum_s[(loc << 2) + q] = ss;
  }
  __syncthreads();

  if (q < 8){ // final_attn
    const float* npsr = nps_s + (loc << 8);
    float f = 0.f;
    for (int kp = 0; kp < 4; kp++){
      int p = sel_s[(loc << 2) + kp];
      f += tkw_s[(loc << 2) + kp] * expf(npsr[p * 8 + q] - rmax_s[(loc << 2) + kp]) / rsum_s[(loc << 2) + kp];
    }
    fa_s[(loc << 3) + q] = f;
  }
  __syncthreads();

  if (q < 8){ // g = fa @ attn
    float g = 0.f;
    for (int qq = 0; qq < 8; qq++) g += fa_s[(loc << 3) + qq] * attn_s[(loc << 6) + qq * 8 + q];
    g_s[(loc << 3) + q] = g;
  }
  __syncthreads();

  // gsn: each wave handles its pair's 2 tokens; SNB rows are L1/L2-hot
  for (int tl = 0; tl < 2; tl++){
    const int tkl = (w << 1) + tl;
    const size_t tok = (size_t)tok0 + tkl;
    float o[16];
#pragma unroll
    for (int i = 0; i < 16; i++) o[i] = 0.f;
#pragma unroll
    for (int k = 0; k < 8; k++){
      float gk = g_s[(tkl << 3) + k];
      const uint4* src = (const uint4*)(SNB + ((tok << 3) + k) * 1024 + (l << 4));
      float f0[8], f1[8];
      unpack8(src[0], f0);
      unpack8(src[1], f1);
#pragma unroll
      for (int i = 0; i < 8; i++){ o[i] += gk * f0[i]; o[8 + i] += gk * f1[i]; }
    }
    uint4* dst = (uint4*)(GSN + tok * 1024 + (l << 4));
    dst[0] = pack8(o);
    dst[1] = pack8(o + 8);
  }
}

extern "C" void kernel_launch(void* const* d_in, const int* in_sizes, int n_in,
                              void* d_out, int out_size, void* d_ws, size_t ws_size,
                              hipStream_t stream){
  (void)in_sizes; (void)n_in; (void)out_size; (void)ws_size;
  const float* x   = (const float*)d_in[0];
  const float* tw  = (const float*)d_in[3];
  const float* SN  = (const float*)d_in[4];
  const float* ctx = (const float*)d_in[5];
  const float* Wq  = (const float*)d_in[6];
  const float* bq  = (const float*)d_in[7];
  const float* Wk  = (const float*)d_in[8];
  const float* Wv  = (const float*)d_in[10];
  const float* bv  = (const float*)d_in[11];
  const float* pat = (const float*)d_in[12];
  const float* Wup = (const float*)d_in[13];
  const float* bup = (const float*)d_in[14];
  const float* Wdn = (const float*)d_in[15];
  const float* bdn = (const float*)d_in[16];
  float* out = (float*)d_out;

  char* ws = (char*)d_ws;
  size_t off = 0;
  auto alloc = [&](size_t bytes) -> char* {
    char* p = ws + off;
    off = (off + bytes + 255) & ~(size_t)255;
    return p;
  };
  ushort_t* SNB  = (ushort_t*)alloc(67108864);  // SN bf16 [32768][1024]; later aliased by H
  ushort_t* TB   = (ushort_t*)alloc(67108864);  // T bf16; later aliased by COMBINED
  float*    CBb  = (float*)alloc(524288);       // [4096][32]
  ushort_t* GSN  = (ushort_t*)alloc(8388608);   // [4096][1024] bf16
  ushort_t* CTXB = (ushort_t*)alloc(8388608);
  ushort_t* PATB = (ushort_t*)alloc(65536);
  ushort_t* WVB  = (ushort_t*)alloc(2097152);
  ushort_t* WUPB = (ushort_t*)alloc(8388608);
  ushort_t* WDNB = (ushort_t*)alloc(8388608);
  ushort_t* ATB  = (ushort_t*)alloc(2097152);
  ushort_t* WKTB = (ushort_t*)alloc(2097152);
  ushort_t* WQTB = (ushort_t*)alloc(2097152);
  ushort_t* WVTB = (ushort_t*)alloc(2097152);
  ushort_t* PVB  = (ushort_t*)alloc(65536);
  float*    WVEC = (float*)alloc(4096);
  float*    PBv  = (float*)alloc(128);
  ushort_t* H    = SNB;   // 32MB alias (SNB dead by FFN time)
  ushort_t* CMB  = TB;    // 8MB alias (T dead after k_attn)

  // converts + out-init (one launch), transposes (one), prep (one)
  const int e0 = 8388608, e1 = e0 + 1048576, e2 = e1 + 8192,
            e3 = e2 + 262144, e4 = e3 + 1048576, e5 = e4 + 1048576,
            e6 = e5 + 1048576;   // out fill: 4096*1024/4
  k_cvt_multi<<<(e6 + 255) / 256, 256, 0, stream>>>(
      SN, SNB, e0, ctx, CTXB, e1, pat, PATB, e2,
      Wv, WVB, e3, Wup, WUPB, e4, Wdn, WDNB, e5, bdn, out, e6);
  k_transpose3<<<dim3(32, 32, 3), 256, 0, stream>>>(Wq, WQTB, Wk, WKTB, Wv, WVTB);
  k_prep<<<520, 256, 0, stream>>>(bq, WKTB, WVEC, pat, bv, PBv, WVTB, PATB, PVB);

  // At[d'][d] = sum_e Wk[e][d']*Wq[e][d]   (64x128 tiles, 128 blocks)
  k_gemm_bt64<0, 8, 1><<<128, 256, 0, stream>>>(WKTB, WQTB, ATB, nullptr, nullptr, 1024, 1024);
  // T = SN @ At^T + wvec  (B = 2MB, L2-resident; NG=GN -> plain order)
  k_gemm_bt<1, 8, 8><<<2048, 256, 0, stream>>>(SNB, ATB, TB, WVEC, nullptr, 1024, 1024);
  // CB[tok][p] = context[tok] . pattern[p]
  k_gemm_n32<<<32, 256, 0, stream>>>(CTXB, PATB, CBb, 1024);
  // fused: logits+NPRE (MFMA) -> softmax/top-4/final_attn -> gsn
  k_attn<<<512, 256, 0, stream>>>(TB, SNB, PVB, PBv, CBb, tw, GSN);
  // combined = gsn @ Wv^T + bv + x   (bf16, 64x128 tiles, 512 blocks)
  k_gemm_bt64<2, 8, 1><<<512, 256, 0, stream>>>(GSN, WVB, CMB, bv, x, 1024, 1024);
  // H = gelu(combined @ Wup^T + bup)  (n-groups of 4 -> B L2-resident)
  k_gemm_bt<3, 32, 4><<<1024, 256, 0, stream>>>(CMB, WUPB, H, bup, nullptr, 4096, 1024);
  // out += H @ Wdown^T  (split-K=2, fp32 atomics; bdn pre-filled by cvt kernel)
  k_gemm_bt64<5, 8, 2><<<1024, 256, 0, stream>>>(H, WDNB, out, nullptr, nullptr, 1024, 4096);
}

// Round 6
// 584.954 us; speedup vs baseline: 1.5147x; 1.0775x over previous
//
#include <hip/hip_runtime.h>
#include <math.h>

// B=2,S=2048 -> NT=4096 tokens; K=8, D=1024, P=32, KP=4, DFF=4096
typedef unsigned short ushort_t;
typedef __attribute__((ext_vector_type(8))) short short8;
typedef __attribute__((ext_vector_type(4))) float floatx4;

static __device__ __forceinline__ ushort_t f2bf(float f){
  unsigned int u = __float_as_uint(f);
  unsigned int r = u + 0x7FFFu + ((u >> 16) & 1u);   // round-to-nearest-even
  return (ushort_t)(r >> 16);
}
static __device__ __forceinline__ void unpack8(uint4 u, float* f){
  f[0] = __uint_as_float(u.x << 16); f[1] = __uint_as_float(u.x & 0xffff0000u);
  f[2] = __uint_as_float(u.y << 16); f[3] = __uint_as_float(u.y & 0xffff0000u);
  f[4] = __uint_as_float(u.z << 16); f[5] = __uint_as_float(u.z & 0xffff0000u);
  f[6] = __uint_as_float(u.w << 16); f[7] = __uint_as_float(u.w & 0xffff0000u);
}
static __device__ __forceinline__ uint4 pack8(const float* f){
  uint4 u;
  u.x = (unsigned)f2bf(f[0]) | ((unsigned)f2bf(f[1]) << 16);
  u.y = (unsigned)f2bf(f[2]) | ((unsigned)f2bf(f[3]) << 16);
  u.z = (unsigned)f2bf(f[4]) | ((unsigned)f2bf(f[5]) << 16);
  u.w = (unsigned)f2bf(f[6]) | ((unsigned)f2bf(f[7]) << 16);
  return u;
}

static __device__ __forceinline__ void gload16(const void* g, void* l){
  __builtin_amdgcn_global_load_lds((const __attribute__((address_space(1))) void*)g,
                                   (__attribute__((address_space(3))) void*)l, 16, 0, 0);
}

// gelu(x) ~= x * sigmoid(1.5957691216 x + 0.0713548162 x^3)  (tanh form, hw exp)
static __device__ __forceinline__ float gelu_f(float v){
  float w = v * (-1.5957691216f - 0.0713548162f * v * v);
  return v / (1.0f + __expf(w));
}

// ------------- merged fp32 -> bf16 converts (6 tensors, one launch) ----------
__global__ __launch_bounds__(256) void k_cvt_multi(
    const float* __restrict__ s0, ushort_t* __restrict__ d0, int e0,
    const float* __restrict__ s1, ushort_t* __restrict__ d1, int e1,
    const float* __restrict__ s2, ushort_t* __restrict__ d2, int e2,
    const float* __restrict__ s3, ushort_t* __restrict__ d3, int e3,
    const float* __restrict__ s4, ushort_t* __restrict__ d4, int e4,
    const float* __restrict__ s5, ushort_t* __restrict__ d5, int e5){
  int i = blockIdx.x * 256 + threadIdx.x;
  const float* s; ushort_t* d; int b;
  if      (i < e0){ s = s0; d = d0; b = 0;  }
  else if (i < e1){ s = s1; d = d1; b = e0; }
  else if (i < e2){ s = s2; d = d2; b = e1; }
  else if (i < e3){ s = s3; d = d3; b = e2; }
  else if (i < e4){ s = s4; d = d4; b = e3; }
  else if (i < e5){ s = s5; d = d5; b = e4; }
  else return;
  int j = i - b;
  float4 v = ((const float4*)s)[j];
  unsigned long long p = (unsigned long long)f2bf(v.x)
                       | ((unsigned long long)f2bf(v.y) << 16)
                       | ((unsigned long long)f2bf(v.z) << 32)
                       | ((unsigned long long)f2bf(v.w) << 48);
  ((unsigned long long*)d)[j] = p;
}

// ---------------- 3x 1024x1024 transpose with bf16 convert (one launch) -------
__global__ __launch_bounds__(256) void k_transpose3(const float* __restrict__ s0, ushort_t* __restrict__ d0,
                                                    const float* __restrict__ s1, ushort_t* __restrict__ d1,
                                                    const float* __restrict__ s2, ushort_t* __restrict__ d2){
  __shared__ float tile[32][33];
  const float* in; ushort_t* out;
  if      (blockIdx.z == 0){ in = s0; out = d0; }
  else if (blockIdx.z == 1){ in = s1; out = d1; }
  else                     { in = s2; out = d2; }
  int bx = blockIdx.x * 32, by = blockIdx.y * 32;
  int tx = threadIdx.x & 31, ty = threadIdx.x >> 5;   // ty 0..7
  for (int i = 0; i < 32; i += 8)
    tile[ty + i][tx] = in[(size_t)(by + ty + i) * 1024 + bx + tx];
  __syncthreads();
  for (int i = 0; i < 32; i += 8)
    out[(size_t)(bx + ty + i) * 1024 + by + tx] = f2bf(tile[tx][ty + i]);
}

// -------- merged prep: wvec (256) | pb (8) | PV (256) | CB n32-GEMM (32) ------
__global__ __launch_bounds__(256) void k_prep(const float* __restrict__ bq,
                                              const ushort_t* __restrict__ WKT,
                                              float* __restrict__ wv,
                                              const float* __restrict__ pat,
                                              const float* __restrict__ bv,
                                              float* __restrict__ pb,
                                              const ushort_t* __restrict__ WVT,
                                              const ushort_t* __restrict__ PATB,
                                              ushort_t* __restrict__ PVB,
                                              const ushort_t* __restrict__ CTXB,
                                              float* __restrict__ CBb){
  __shared__ ushort_t As[128 * 32];
  __shared__ ushort_t Bs[32 * 32];
  const int bid = blockIdx.x;
  const int l = threadIdx.x & 63;
  if (bid < 256){            // wvec
    int d = (bid << 2) + (threadIdx.x >> 6);
    const uint4* row = (const uint4*)(WKT + (size_t)d * 1024 + (l << 4));
    const float4* b4 = (const float4*)(bq + (l << 4));
    float w[16], bb[16];
    unpack8(row[0], w); unpack8(row[1], w + 8);
#pragma unroll
    for (int i = 0; i < 4; i++){
      float4 v = b4[i];
      bb[i*4] = v.x; bb[i*4+1] = v.y; bb[i*4+2] = v.z; bb[i*4+3] = v.w;
    }
    float a = 0.f;
#pragma unroll
    for (int i = 0; i < 16; i++) a += w[i] * bb[i];
#pragma unroll
    for (int s = 1; s < 64; s <<= 1) a += __shfl_xor(a, s);
    if (l == 0) wv[d] = a;
  } else if (bid < 264){     // pb
    int p = ((bid - 256) << 2) + (threadIdx.x >> 6);
    const float4* pr = (const float4*)(pat + p * 1024) + l;
    const float4* b4 = (const float4*)bv + l;
    float a = 0.f;
#pragma unroll
    for (int i = 0; i < 4; i++){
      float4 x = pr[i * 64], y = b4[i * 64];
      a += x.x * y.x + x.y * y.y + x.z * y.z + x.w * y.w;
    }
#pragma unroll
    for (int s = 1; s < 64; s <<= 1) a += __shfl_xor(a, s);
    if (l == 0) pb[p] = a;
  } else if (bid < 520){     // PV
    int d = ((bid - 264) << 2) + (threadIdx.x >> 6);
    const uint4* wr = (const uint4*)(WVT + (size_t)d * 1024 + (l << 4));
    float w[16];
    unpack8(wr[0], w); unpack8(wr[1], w + 8);
    for (int p = 0; p < 32; p++){
      const uint4* pr = (const uint4*)(PATB + p * 1024 + (l << 4));
      float pw[16];
      unpack8(pr[0], pw); unpack8(pr[1], pw + 8);
      float a = 0.f;
#pragma unroll
      for (int i = 0; i < 16; i++) a += w[i] * pw[i];
#pragma unroll
      for (int s = 1; s < 64; s <<= 1) a += __shfl_xor(a, s);
      if (l == 0) PVB[p * 1024 + d] = f2bf(a);
    }
  } else {                   // CB[tok][p] = ctx_tok . pat_p  (n32 MFMA GEMM)
    const int tid = threadIdx.x;
    const int w = tid >> 6;
    const int m0 = (bid - 520) << 7;
    const int rA = (w << 4) + (l >> 2);
    const int cA = (l & 3) << 3;
    const int fr = l & 15, fq = l >> 4;
    const int K = 1024;
    floatx4 acc[2][2];
#pragma unroll
    for (int i = 0; i < 2; i++)
#pragma unroll
      for (int j = 0; j < 2; j++) acc[i][j] = (floatx4)0.0f;
    const ushort_t* Ab = CTXB + (size_t)(m0 + rA) * K + cA;
    const ushort_t* Bb = PATB + (size_t)rA * K + cA;
    const size_t row64 = (size_t)64 * K;
    for (int k0 = 0; k0 < K; k0 += 32){
      __syncthreads();
      gload16(Ab + k0, As + (w << 9));
      gload16(Ab + row64 + k0, As + 2048 + (w << 9));
      if (w < 2) gload16(Bb + k0, Bs + (w << 9));
      __syncthreads();
      short8 af[2], bg[2];
#pragma unroll
      for (int i = 0; i < 2; i++)
        af[i] = *(const short8*)(As + (((w << 5) + (i << 4) + fr) << 5) + (fq << 3));
#pragma unroll
      for (int j = 0; j < 2; j++)
        bg[j] = *(const short8*)(Bs + (((j << 4) + fr) << 5) + (fq << 3));
#pragma unroll
      for (int i = 0; i < 2; i++)
#pragma unroll
        for (int j = 0; j < 2; j++)
          acc[i][j] = __builtin_amdgcn_mfma_f32_16x16x32_bf16(af[i], bg[j], acc[i][j], 0, 0, 0);
    }
#pragma unroll
    for (int i = 0; i < 2; i++){
      int row = m0 + (w << 5) + (i << 4) + (fq << 2);
#pragma unroll
      for (int j = 0; j < 2; j++){
        int col = (j << 4) + fr;
#pragma unroll
        for (int r = 0; r < 4; r++)
          CBb[(size_t)(row + r) * 32 + col] = acc[i][j][r];
      }
    }
  }
}

// ---------------- main bf16 GEMM (128x128 tile, BK=64 double-stage) ----------
// 1D grid, XCD swizzle + n-group-of-NG for L2 reuse of B.
// MODE 0: bf16(acc) 1: bf16(acc+bias) 2: bf16(acc+bias+Xadd) 3: bf16(gelu) 4: fp32(acc+bias)
template<int MODE, int GN, int NG>
__global__ __launch_bounds__(256) void k_gemm_bt(const ushort_t* __restrict__ A,
                                                 const ushort_t* __restrict__ B,
                                                 void* __restrict__ C,
                                                 const float* __restrict__ bias,
                                                 const float* __restrict__ Xadd,
                                                 int N, int K){
  __shared__ ushort_t As[2 * 128 * 32];   // 16 KB
  __shared__ ushort_t Bs[2 * 128 * 32];   // 16 KB
  const int tid = threadIdx.x;
  const int w = tid >> 6, l = tid & 63;
  const int id = blockIdx.x;
  const int xcd = id & 7;
  const int t2 = id >> 3;
  const int nmq = (int)(gridDim.x >> 3) / GN;   // m-tile count per XCD
  const int gsz = nmq * NG;
  const int g = t2 / gsz, r = t2 - g * gsz;
  const int mq = r / NG, nw = r - mq * NG;
  const int nt = g * NG + nw;
  const int mt = (mq << 3) + xcd;
  const int m0 = mt << 7, n0 = nt << 7;
  const int wm = (w >> 1) << 6, wn = (w & 1) << 6;
  const int rA = (w << 4) + (l >> 2);
  const int cA = (l & 3) << 3;
  const int fr = l & 15, fq = l >> 4;

  floatx4 acc[4][4];
#pragma unroll
  for (int i = 0; i < 4; i++)
#pragma unroll
    for (int j = 0; j < 4; j++) acc[i][j] = (floatx4)0.0f;

  const ushort_t* Ab = A + (size_t)(m0 + rA) * K + cA;
  const ushort_t* Bb = B + (size_t)(n0 + rA) * K + cA;
  const size_t row64 = (size_t)64 * K;
  ushort_t* Asw = As + (w << 9);
  ushort_t* Bsw = Bs + (w << 9);

  for (int k0 = 0; k0 < K; k0 += 64){
    __syncthreads();
    gload16(Ab + k0, Asw);
    gload16(Ab + row64 + k0, Asw + 2048);
    gload16(Ab + k0 + 32, Asw + 4096);
    gload16(Ab + row64 + k0 + 32, Asw + 6144);
    gload16(Bb + k0, Bsw);
    gload16(Bb + row64 + k0, Bsw + 2048);
    gload16(Bb + k0 + 32, Bsw + 4096);
    gload16(Bb + row64 + k0 + 32, Bsw + 6144);
    __syncthreads();
#pragma unroll
    for (int h = 0; h < 2; h++){
      const ushort_t* Ah = As + (h << 12);
      const ushort_t* Bh = Bs + (h << 12);
      short8 af[4], bg[4];
#pragma unroll
      for (int i = 0; i < 4; i++){
        af[i] = *(const short8*)(Ah + ((wm + (i << 4) + fr) << 5) + (fq << 3));
        bg[i] = *(const short8*)(Bh + ((wn + (i << 4) + fr) << 5) + (fq << 3));
      }
#pragma unroll
      for (int i = 0; i < 4; i++)
#pragma unroll
        for (int j = 0; j < 4; j++)
          acc[i][j] = __builtin_amdgcn_mfma_f32_16x16x32_bf16(af[i], bg[j], acc[i][j], 0, 0, 0);
    }
  }

#pragma unroll
  for (int i = 0; i < 4; i++){
    int row = m0 + wm + (i << 4) + (fq << 2);
#pragma unroll
    for (int j = 0; j < 4; j++){
      int col = n0 + wn + (j << 4) + fr;
      float b = (MODE >= 1) ? bias[col] : 0.0f;
#pragma unroll
      for (int r2 = 0; r2 < 4; r2++){
        float v = acc[i][j][r2] + b;
        size_t idx = (size_t)(row + r2) * N + col;
        if (MODE == 2) v += Xadd[idx];
        if (MODE == 3) v = gelu_f(v);
        if (MODE == 4) ((float*)C)[idx] = v;
        else           ((ushort_t*)C)[idx] = f2bf(v);
      }
    }
  }
}

// ---------- 64x128-tile GEMM, BK=64 double-stage (small-M shapes) ------------
// Per-XCD enumeration nt-outer -> B-tile L2-resident across the mq sweep.
// MODE 0: bf16(acc) 2: bf16(acc+bias+Xadd) 4: fp32(acc+bias)
template<int MODE, int GN>
__global__ __launch_bounds__(256) void k_gemm_bt64(const ushort_t* __restrict__ A,
                                                   const ushort_t* __restrict__ B,
                                                   void* __restrict__ C,
                                                   const float* __restrict__ bias,
                                                   const float* __restrict__ Xadd,
                                                   int N, int K){
  __shared__ ushort_t As[2 * 64 * 32];    // 8 KB
  __shared__ ushort_t Bs[2 * 128 * 32];   // 16 KB
  const int tid = threadIdx.x;
  const int w = tid >> 6, l = tid & 63;
  const int id = blockIdx.x;
  const int xcd = id & 7;
  const int t2 = id >> 3;
  const int nmq = (int)(gridDim.x >> 3) / GN;
  const int nt = t2 / nmq;
  const int mq = t2 - nt * nmq;
  const int mt = (mq << 3) + xcd;
  const int m0 = mt << 6, n0 = nt << 7;
  const int wm = (w >> 1) << 5, wn = (w & 1) << 6;   // wave: 32x64 of the 64x128 tile
  const int rA = (w << 4) + (l >> 2);
  const int cA = (l & 3) << 3;
  const int fr = l & 15, fq = l >> 4;

  floatx4 acc[2][4];
#pragma unroll
  for (int i = 0; i < 2; i++)
#pragma unroll
    for (int j = 0; j < 4; j++) acc[i][j] = (floatx4)0.0f;

  const ushort_t* Ab = A + (size_t)(m0 + rA) * K + cA;
  const ushort_t* Bb = B + (size_t)(n0 + rA) * K + cA;
  const size_t row64 = (size_t)64 * K;

  for (int k0 = 0; k0 < K; k0 += 64){
    __syncthreads();
    gload16(Ab + k0, As + (w << 9));
    gload16(Ab + k0 + 32, As + 2048 + (w << 9));
    gload16(Bb + k0, Bs + (w << 9));
    gload16(Bb + row64 + k0, Bs + 2048 + (w << 9));
    gload16(Bb + k0 + 32, Bs + 4096 + (w << 9));
    gload16(Bb + row64 + k0 + 32, Bs + 6144 + (w << 9));
    __syncthreads();
#pragma unroll
    for (int h = 0; h < 2; h++){
      const ushort_t* Ah = As + (h << 11);
      const ushort_t* Bh = Bs + (h << 12);
      short8 af[2], bg[4];
#pragma unroll
      for (int i = 0; i < 2; i++)
        af[i] = *(const short8*)(Ah + ((wm + (i << 4) + fr) << 5) + (fq << 3));
#pragma unroll
      for (int j = 0; j < 4; j++)
        bg[j] = *(const short8*)(Bh + ((wn + (j << 4) + fr) << 5) + (fq << 3));
#pragma unroll
      for (int i = 0; i < 2; i++)
#pragma unroll
        for (int j = 0; j < 4; j++)
          acc[i][j] = __builtin_amdgcn_mfma_f32_16x16x32_bf16(af[i], bg[j], acc[i][j], 0, 0, 0);
    }
  }

#pragma unroll
  for (int i = 0; i < 2; i++){
    int row = m0 + wm + (i << 4) + (fq << 2);
#pragma unroll
    for (int j = 0; j < 4; j++){
      int col = n0 + wn + (j << 4) + fr;
      float b = (MODE >= 2) ? bias[col] : 0.0f;
#pragma unroll
      for (int r = 0; r < 4; r++){
        float v = acc[i][j][r] + b;
        size_t idx = (size_t)(row + r) * N + col;
        if (MODE == 2) v += Xadd[idx];
        if (MODE == 4) ((float*)C)[idx] = v;
        else           ((ushort_t*)C)[idx] = f2bf(v);
      }
    }
  }
}

// ---------------- fused attention: logits+NPRE (MFMA) -> softmax/top-4 -> gsn -
__global__ __launch_bounds__(256) void k_attn(const ushort_t* __restrict__ T,
                                              const ushort_t* __restrict__ SNB,
                                              const ushort_t* __restrict__ PVB,
                                              const float* __restrict__ PBv,
                                              const float* __restrict__ CB,
                                              const float* __restrict__ TW,
                                              ushort_t* __restrict__ GSN){
  __shared__ float logit_s[4 * 256];
  __shared__ float attn_s[8 * 64];
  __shared__ float npr_s[8 * 256];
  __shared__ float nps_s[8 * 256];
  __shared__ float sc_s[8 * 32];
  __shared__ float tw_s[8 * 8];
  __shared__ float pb_s[32];
  __shared__ int   sel_s[8 * 4];
  __shared__ float tkw_s[8 * 4], rmax_s[8 * 4], rsum_s[8 * 4], fa_s[8 * 8], g_s[8 * 8];

  const int t = threadIdx.x;
  const int w = t >> 6, l = t & 63;
  const int tok0 = blockIdx.x << 3;
  const int pair = (blockIdx.x << 2) + w;

  { // MFMA: logits + NPRE for this wave's pair, fragments straight from global
    const size_t rbase = (size_t)pair * 16 + (l & 15);
    const int ko = (l >> 4) << 3;
    const ushort_t* Ap = T   + rbase * 1024 + ko;
    const ushort_t* Bp = SNB + rbase * 1024 + ko;
    const ushort_t* P0 = PVB + (size_t)(l & 15) * 1024 + ko;          // patterns 0-15
    const ushort_t* P1 = P0 + 16 * 1024;                              // patterns 16-31
    floatx4 aL = (floatx4)0.0f, aP0 = (floatx4)0.0f, aP1 = (floatx4)0.0f;
#pragma unroll 4
    for (int k0 = 0; k0 < 1024; k0 += 32){
      short8 b = *(const short8*)(Bp + k0);
      aL  = __builtin_amdgcn_mfma_f32_16x16x32_bf16(*(const short8*)(Ap + k0), b, aL, 0, 0, 0);
      aP0 = __builtin_amdgcn_mfma_f32_16x16x32_bf16(*(const short8*)(P0 + k0), b, aP0, 0, 0, 0);
      aP1 = __builtin_amdgcn_mfma_f32_16x16x32_bf16(*(const short8*)(P1 + k0), b, aP1, 0, 0, 0);
    }
    const int col = l & 15, r0 = (l >> 4) << 2;
#pragma unroll
    for (int r = 0; r < 4; r++)
      logit_s[(w << 8) + (r0 + r) * 16 + col] = aL[r] * 0.03125f;
    // NPRE: D[i][j] = PV_i . SN_j ; j -> (token j>>3, k=j&7), i -> pattern
    const int tokloc = (w << 1) + (col >> 3), kk = col & 7;
#pragma unroll
    for (int r = 0; r < 4; r++){
      npr_s[(tokloc << 8) + kk * 32 + (r0 + r)]      = aP0[r];
      npr_s[(tokloc << 8) + kk * 32 + (r0 + r) + 16] = aP1[r];
    }
  }
  if (t < 64) tw_s[t] = TW[(tok0 << 3) + t];
  if (t < 32) pb_s[t] = PBv[t];
  __syncthreads();

  const int loc = t >> 5, q = t & 31;    // token-in-block, lane-in-token-group
  if (q < 8){ // softmax of logit row q for token loc
    const float* lrow = logit_s + ((loc >> 1) << 8) + (loc & 1) * 136 + q * 16;
    float a[8]; float m = -1e30f;
#pragma unroll
    for (int j = 0; j < 8; j++){ a[j] = lrow[j]; m = fmaxf(m, a[j]); }
    float s = 0.f;
#pragma unroll
    for (int j = 0; j < 8; j++){ a[j] = expf(a[j] - m); s += a[j]; }
    float inv = 1.f / s;
#pragma unroll
    for (int j = 0; j < 8; j++) attn_s[(loc << 6) + q * 8 + j] = a[j] * inv;
  }
  __syncthreads();

  { // nps: column qq = q&7, patterns (q>>3)*8..+7 ; +pb (rows of attn sum to 1)
    const int qq = q & 7, p0 = (q >> 3) << 3;
    float a[8];
#pragma unroll
    for (int k = 0; k < 8; k++) a[k] = attn_s[(loc << 6) + qq * 8 + k];
    const float* np = npr_s + (loc << 8);
    float* npsr = nps_s + (loc << 8);
    for (int p = p0; p < p0 + 8; p++){
      float acc = pb_s[p];
#pragma unroll
      for (int k = 0; k < 8; k++) acc += a[k] * np[k * 32 + p];
      npsr[p * 8 + qq] = acc * 0.03125f;
    }
  }
  __syncthreads();

  { // scores, p = q
    const float* npsr = nps_s + (loc << 8);
    float nb = 0.f;
#pragma unroll
    for (int qq = 0; qq < 8; qq++) nb += npsr[q * 8 + qq] * tw_s[(loc << 3) + qq];
    sc_s[(loc << 5) + q] = 0.5f * nb + 0.5f * CB[((size_t)(tok0 + loc) << 5) + q];
  }
  __syncthreads();

  if (q == 0){ // top-4 (stable: first index wins ties, like lax.top_k)
    const float* sc = sc_s + (loc << 5);
    unsigned used = 0; float vals[4]; int idx[4];
    for (int kp = 0; kp < 4; kp++){
      float best = -1e30f; int bi = 0;
      for (int p = 0; p < 32; p++)
        if (!((used >> p) & 1u) && sc[p] > best){ best = sc[p]; bi = p; }
      used |= 1u << bi; vals[kp] = best; idx[kp] = bi;
    }
    float mm = vals[0], ss = 0.f, e[4];
    for (int kp = 0; kp < 4; kp++){ e[kp] = expf(vals[kp] - mm); ss += e[kp]; }
    for (int kp = 0; kp < 4; kp++){ tkw_s[(loc << 2) + kp] = e[kp] / ss; sel_s[(loc << 2) + kp] = idx[kp]; }
  }
  __syncthreads();

  if (q < 4){ // row softmax stats for selected patterns
    const float* npsr = nps_s + (loc << 8);
    int p = sel_s[(loc << 2) + q];
    float mm = -1e30f;
    for (int j = 0; j < 8; j++) mm = fmaxf(mm, npsr[p * 8 + j]);
    float ss = 0.f;
    for (int j = 0; j < 8; j++) ss += expf(npsr[p * 8 + j] - mm);
    rmax_s[(loc << 2) + q] = mm; rsum_s[(loc << 2) + q] = ss;
  }
  __syncthreads();

  if (q < 8){ // final_attn
    const float* npsr = nps_s + (loc << 8);
    float f = 0.f;
    for (int kp = 0; kp < 4; kp++){
      int p = sel_s[(loc << 2) + kp];
      f += tkw_s[(loc << 2) + kp] * expf(npsr[p * 8 + q] - rmax_s[(loc << 2) + kp]) / rsum_s[(loc << 2) + kp];
    }
    fa_s[(loc << 3) + q] = f;
  }
  __syncthreads();

  if (q < 8){ // g = fa @ attn
    float g = 0.f;
    for (int qq = 0; qq < 8; qq++) g += fa_s[(loc << 3) + qq] * attn_s[(loc << 6) + qq * 8 + q];
    g_s[(loc << 3) + q] = g;
  }
  __syncthreads();

  // gsn: each wave handles its pair's 2 tokens; SNB rows are L1/L2-hot
  for (int tl = 0; tl < 2; tl++){
    const int tkl = (w << 1) + tl;
    const size_t tok = (size_t)tok0 + tkl;
    float o[16];
#pragma unroll
    for (int i = 0; i < 16; i++) o[i] = 0.f;
#pragma unroll
    for (int k = 0; k < 8; k++){
      float gk = g_s[(tkl << 3) + k];
      const uint4* src = (const uint4*)(SNB + ((tok << 3) + k) * 1024 + (l << 4));
      float f0[8], f1[8];
      unpack8(src[0], f0);
      unpack8(src[1], f1);
#pragma unroll
      for (int i = 0; i < 8; i++){ o[i] += gk * f0[i]; o[8 + i] += gk * f1[i]; }
    }
    uint4* dst = (uint4*)(GSN + tok * 1024 + (l << 4));
    dst[0] = pack8(o);
    dst[1] = pack8(o + 8);
  }
}

extern "C" void kernel_launch(void* const* d_in, const int* in_sizes, int n_in,
                              void* d_out, int out_size, void* d_ws, size_t ws_size,
                              hipStream_t stream){
  (void)in_sizes; (void)n_in; (void)out_size; (void)ws_size;
  const float* x   = (const float*)d_in[0];
  const float* tw  = (const float*)d_in[3];
  const float* SN  = (const float*)d_in[4];
  const float* ctx = (const float*)d_in[5];
  const float* Wq  = (const float*)d_in[6];
  const float* bq  = (const float*)d_in[7];
  const float* Wk  = (const float*)d_in[8];
  const float* Wv  = (const float*)d_in[10];
  const float* bv  = (const float*)d_in[11];
  const float* pat = (const float*)d_in[12];
  const float* Wup = (const float*)d_in[13];
  const float* bup = (const float*)d_in[14];
  const float* Wdn = (const float*)d_in[15];
  const float* bdn = (const float*)d_in[16];
  float* out = (float*)d_out;

  char* ws = (char*)d_ws;
  size_t off = 0;
  auto alloc = [&](size_t bytes) -> char* {
    char* p = ws + off;
    off = (off + bytes + 255) & ~(size_t)255;
    return p;
  };
  ushort_t* SNB  = (ushort_t*)alloc(67108864);  // SN bf16 [32768][1024]; later aliased by H
  ushort_t* TB   = (ushort_t*)alloc(67108864);  // T bf16; later aliased by COMBINED
  float*    CBb  = (float*)alloc(524288);       // [4096][32]
  ushort_t* GSN  = (ushort_t*)alloc(8388608);   // [4096][1024] bf16
  ushort_t* CTXB = (ushort_t*)alloc(8388608);
  ushort_t* PATB = (ushort_t*)alloc(65536);
  ushort_t* WVB  = (ushort_t*)alloc(2097152);
  ushort_t* WUPB = (ushort_t*)alloc(8388608);
  ushort_t* WDNB = (ushort_t*)alloc(8388608);
  ushort_t* ATB  = (ushort_t*)alloc(2097152);
  ushort_t* WKTB = (ushort_t*)alloc(2097152);
  ushort_t* WQTB = (ushort_t*)alloc(2097152);
  ushort_t* WVTB = (ushort_t*)alloc(2097152);
  ushort_t* PVB  = (ushort_t*)alloc(65536);
  float*    WVEC = (float*)alloc(4096);
  float*    PBv  = (float*)alloc(128);
  ushort_t* H    = SNB;   // 32MB alias (SNB dead by FFN time)
  ushort_t* CMB  = TB;    // 8MB alias (T dead after k_attn)

  // converts (one launch) + transposes (one) + prep incl. CB (one)
  const int e0 = 8388608, e1 = e0 + 1048576, e2 = e1 + 8192,
            e3 = e2 + 262144, e4 = e3 + 1048576, e5 = e4 + 1048576;
  k_cvt_multi<<<(e5 + 255) / 256, 256, 0, stream>>>(
      SN, SNB, e0, ctx, CTXB, e1, pat, PATB, e2,
      Wv, WVB, e3, Wup, WUPB, e4, Wdn, WDNB, e5);
  k_transpose3<<<dim3(32, 32, 3), 256, 0, stream>>>(Wq, WQTB, Wk, WKTB, Wv, WVTB);
  k_prep<<<552, 256, 0, stream>>>(bq, WKTB, WVEC, pat, bv, PBv, WVTB, PATB, PVB, CTXB, CBb);

  // At[d'][d] = sum_e Wk[e][d']*Wq[e][d]   (64x128 tiles, 128 blocks)
  k_gemm_bt64<0, 8><<<128, 256, 0, stream>>>(WKTB, WQTB, ATB, nullptr, nullptr, 1024, 1024);
  // T = SN @ At^T + wvec  (B = 2MB, L2-resident)
  k_gemm_bt<1, 8, 8><<<2048, 256, 0, stream>>>(SNB, ATB, TB, WVEC, nullptr, 1024, 1024);
  // fused: logits+NPRE (MFMA) -> softmax/top-4/final_attn -> gsn
  k_attn<<<512, 256, 0, stream>>>(TB, SNB, PVB, PBv, CBb, tw, GSN);
  // combined = gsn @ Wv^T + bv + x   (bf16, 64x128 tiles, 512 blocks)
  k_gemm_bt64<2, 8><<<512, 256, 0, stream>>>(GSN, WVB, CMB, bv, x, 1024, 1024);
  // H = gelu(combined @ Wup^T + bup)  (n-groups of 4 -> B L2-resident)
  k_gemm_bt<3, 32, 4><<<1024, 256, 0, stream>>>(CMB, WUPB, H, bup, nullptr, 4096, 1024);
  // out = H @ Wdown^T + bdn  (fp32, 64x128 tiles, 512 blocks)
  k_gemm_bt64<4, 8><<<512, 256, 0, stream>>>(H, WDNB, out, bdn, nullptr, 1024, 4096);
}